// Round 2
// baseline (2545.789 us; speedup 1.0000x reference)
//
#include <hip/hip_runtime.h>
#include <cstdint>
#include <cstddef>

#define BB 64
#define PP 8732
#define OO 32
#define CC 81
#define NBM 35    // k_match blocks per image (ceil(8732/256))
#define NB2 273   // k_ce blocks-x per image (32 priors each; 273*32=8736)

// ---------- kernel A: per-prior best object + per-block per-object best prior ----------
// Writes packed olab = (label<<5)|object per prior. label=0 if overlap<0.5.
__global__ __launch_bounds__(256) void k_match(
    const float* __restrict__ gt_boxes,      // [B,O,4] coco pixel
    const int* __restrict__ gt_labels,       // [B,O]
    const float4* __restrict__ priors,       // [P] cxcy
    int* __restrict__ olab,                  // [B,P] packed (lab<<5)|obj
    unsigned long long* __restrict__ part)   // [B,NBM,O] packed (iou_bits<<32)|(~p)
{
    int b = blockIdx.y, blk = blockIdx.x;
    int tid = threadIdx.x;
    int p = blk * 256 + tid;
    bool pv = p < PP;
    __shared__ float bx1[OO], by1[OO], bx2[OO], by2[OO], bar[OO];
    __shared__ int slab[OO];
    __shared__ float mat[OO][264];           // stride 264 -> 2-way banks max (free)
    __shared__ unsigned long long po[OO][8];
    if (tid < OO) {
        const float* g = gt_boxes + ((size_t)b * OO + tid) * 4;
        float x1 = g[0] / 224.0f, y1 = g[1] / 224.0f;
        float x2 = (g[0] + g[2]) / 224.0f, y2 = (g[1] + g[3]) / 224.0f;
        bx1[tid] = x1; by1[tid] = y1; bx2[tid] = x2; by2[tid] = y2;
        bar[tid] = (x2 - x1) * (y2 - y1);
        slab[tid] = gt_labels[b * OO + tid];
    }
    __syncthreads();
    float4 pr = priors[pv ? p : 0];
    float px1 = pr.x - pr.z * 0.5f, py1 = pr.y - pr.w * 0.5f;
    float px2 = pr.x + pr.z * 0.5f, py2 = pr.y + pr.w * 0.5f;
    float parea = (px2 - px1) * (py2 - py1);
    float best = -1.0f; int bo = 0;
    #pragma unroll
    for (int o = 0; o < OO; ++o) {
        float lx = fmaxf(bx1[o], px1), ly = fmaxf(by1[o], py1);
        float rx = fminf(bx2[o], px2), ry = fminf(by2[o], py2);
        float w = fmaxf(rx - lx, 0.0f), h = fmaxf(ry - ly, 0.0f);
        float inter = w * h;
        float iou = inter / (bar[o] + parea - inter);
        iou = pv ? iou : 0.0f;               // invalid priors can't win (and have largest p)
        mat[o][tid] = iou;
        if (iou > best) { best = iou; bo = o; }   // strict > : first max (numpy argmax)
    }
    if (pv) {
        int lab = (best < 0.5f) ? 0 : slab[bo];
        olab[(size_t)b * PP + p] = (lab << 5) | bo;
    }
    __syncthreads();
    // per-object partial argmax over this block's 256 priors
    {
        int o = tid >> 3, j = tid & 7;
        float bv = -1.0f; int bt = 0;
        #pragma unroll
        for (int k = 0; k < 32; ++k) {
            int t = j + 8 * k;               // bank-friendly stride, order-free (we pack index)
            float v = mat[o][t];
            if (v > bv) { bv = v; bt = t; }
        }
        unsigned pg = (unsigned)(blk * 256 + bt);
        po[o][j] = ((unsigned long long)__float_as_uint(bv) << 32)
                 | (unsigned long long)(0xFFFFFFFFu - pg);
    }
    __syncthreads();
    if (tid < OO) {
        unsigned long long m = po[tid][0];
        #pragma unroll
        for (int j = 1; j < 8; ++j) if (po[tid][j] > m) m = po[tid][j];
        part[((size_t)b * NBM + blk) * OO + tid] = m;
    }
}

// ---------- kernel A2: fold partials + forced assignment + zero fused-kernel counters ----------
__global__ void k_force(const unsigned long long* __restrict__ part,
                        const int* __restrict__ gt_labels,
                        int* __restrict__ olab,
                        int* __restrict__ imgcnt, int* __restrict__ done)
{
    int b = blockIdx.x;
    int t = threadIdx.x;
    if (t == 0) imgcnt[b] = 0;           // arrival counter for image b (used by fused k_ce)
    if (b == 0 && t == 1) *done = 0;     // cross-image final-fold counter
    __shared__ int s_pfo[OO];
    __shared__ int s_lab[OO];
    if (t < OO) {
        unsigned long long m = part[((size_t)b * NBM + 0) * OO + t];
        for (int blk = 1; blk < NBM; ++blk) {
            unsigned long long v = part[((size_t)b * NBM + blk) * OO + t];
            if (v > m) m = v;                // packed max: larger iou, then smaller p
        }
        s_pfo[t] = (int)(0xFFFFFFFFu - (unsigned)(m & 0xFFFFFFFFull));
        s_lab[t] = gt_labels[b * OO + t];
    }
    __syncthreads();
    if (t == 0) {
        for (int o = 0; o < OO; ++o) {
            int p = s_pfo[o];
            olab[(size_t)b * PP + p] = (s_lab[o] << 5) | o;   // forced positive, ascending o = last-wins
        }
    }
}

// ---------- kernel B (fused): CE + loc loss, then per-image last block does exact
// ---------- top-K radix select, and the globally-last block folds the final scalar ----------
__global__ __launch_bounds__(256) void k_ce(
    const float* __restrict__ scores,        // [B,P,C]
    const float4* __restrict__ pred_locs,
    const float* __restrict__ gt_boxes,
    const float4* __restrict__ priors,
    const int* __restrict__ olab,
    float* __restrict__ ceneg,
    float* __restrict__ pp_posce, float* __restrict__ pp_sl1,
    int* __restrict__ pp_np,
    float* __restrict__ hard, float* __restrict__ posce_b,
    float* __restrict__ sl1_b, int* __restrict__ n_pos,
    int* __restrict__ imgcnt, int* __restrict__ done,
    float* __restrict__ out)
{
    int b = blockIdx.y;
    int group = threadIdx.x >> 4, lane = threadIdx.x & 15;
    int p0 = blockIdx.x * 32 + group;
    int p1 = p0 + 16;
    bool v0 = p0 < PP, v1 = p1 < PP;
    size_t i0 = (size_t)b * PP + (size_t)(v0 ? p0 : 0);
    size_t i1 = (size_t)b * PP + (size_t)(v1 ? p1 : 0);
    __shared__ float s_posce, s_sl1;
    __shared__ int s_np;
    if (threadIdx.x == 0) { s_posce = 0.f; s_sl1 = 0.f; s_np = 0; }
    __syncthreads();
    int lab0 = 0, ob0 = 0, lab1 = 0, ob1 = 0;
    if (v0) { int v = olab[i0]; ob0 = v & 31; lab0 = v >> 5; }
    if (v1) { int v = olab[i1]; ob1 = v & 31; lab1 = v >> 5; }
    const float* r0 = scores + i0 * CC;
    const float* r1 = scores + i1 * CC;
    float a0[6], a1[6];
    #pragma unroll
    for (int k = 0; k < 6; ++k) {
        int c = lane + 16 * k;
        bool cv = c < CC;
        a0[k] = (v0 && cv) ? r0[c] : -INFINITY;
        a1[k] = (v1 && cv) ? r1[c] : -INFINITY;
    }
    float se0 = 0.f, xl0 = 0.f, se1 = 0.f, xl1 = 0.f;
    #pragma unroll
    for (int k = 0; k < 6; ++k) {
        int c = lane + 16 * k;
        if (c < CC) {
            se0 += __expf(a0[k]); if (c == lab0) xl0 = a0[k];
            se1 += __expf(a1[k]); if (c == lab1) xl1 = a1[k];
        }
    }
    #pragma unroll
    for (int s = 8; s >= 1; s >>= 1) {
        se0 += __shfl_xor(se0, s, 16);
        xl0 += __shfl_xor(xl0, s, 16);
        se1 += __shfl_xor(se1, s, 16);
        xl1 += __shfl_xor(xl1, s, 16);
    }
    if (lane == 0) {
        #pragma unroll
        for (int pass = 0; pass < 2; ++pass) {
            bool vv = pass ? v1 : v0;
            if (!vv) continue;
            size_t idx = pass ? i1 : i0;
            int lab = pass ? lab1 : lab0;
            int ob  = pass ? ob1 : ob0;
            int p   = pass ? p1 : p0;
            float se = pass ? se1 : se0;
            float xl = pass ? xl1 : xl0;
            float ce = fmaxf(__logf(se) - xl, 0.0f);   // >=0 guaranteed (radix assumes)
            float cn = ce;
            if (lab != 0) {
                cn = 0.f;
                float4 pl = pred_locs[idx];
                float4 pq = priors[p];
                const float* g = gt_boxes + ((size_t)b * OO + ob) * 4;
                float x1 = g[0] / 224.0f, y1 = g[1] / 224.0f;
                float x2 = (g[0] + g[2]) / 224.0f, y2 = (g[1] + g[3]) / 224.0f;
                float cx = (x1 + x2) * 0.5f, cy = (y1 + y2) * 0.5f;
                float w = x2 - x1, h = y2 - y1;
                float tx = (cx - pq.x) / (pq.z / 10.0f);
                float ty = (cy - pq.y) / (pq.w / 10.0f);
                float tw = __logf(w / pq.z) * 5.0f;
                float th = __logf(h / pq.w) * 5.0f;
                float d0 = fabsf(pl.x - tx), d1 = fabsf(pl.y - ty);
                float d2 = fabsf(pl.z - tw), d3 = fabsf(pl.w - th);
                float sl = (d0 < 1.f ? 0.5f * d0 * d0 : d0 - 0.5f)
                         + (d1 < 1.f ? 0.5f * d1 * d1 : d1 - 0.5f)
                         + (d2 < 1.f ? 0.5f * d2 * d2 : d2 - 0.5f)
                         + (d3 < 1.f ? 0.5f * d3 * d3 : d3 - 0.5f);
                atomicAdd(&s_posce, ce);   // LDS atomics — per-CU, cheap
                atomicAdd(&s_sl1, sl);
                atomicAdd(&s_np, 1);
            }
            ceneg[idx] = cn;
        }
    }
    __syncthreads();
    if (threadIdx.x == 0) {
        int slot = b * NB2 + blockIdx.x;   // dedicated slot: zero global atomics
        pp_posce[slot] = s_posce;
        pp_sl1[slot]   = s_sl1;
        pp_np[slot]    = s_np;
    }
    // ---- per-image arrival: last block of image b runs the top-K select ----
    __threadfence();                        // release ceneg + pp_* writes
    __shared__ int s_last;
    if (threadIdx.x == 0)
        s_last = (atomicAdd(&imgcnt[b], 1) == NB2 - 1) ? 1 : 0;
    __syncthreads();
    if (!s_last) return;
    __threadfence();                        // acquire other blocks' writes

    int tid = threadIdx.x;
    int wid = tid >> 6;                     // 4 waves
    __shared__ int hist[4][256];            // per-wave histograms (4 KB)
    __shared__ int hsum[256];
    __shared__ int s_i[4];
    __shared__ float s_f[4], s_f2[4];
    __shared__ int s_bcast;
    __shared__ unsigned s_sel;
    __shared__ int s_krem;
    // fold per-block partials for this image
    float pc = 0.f, sl = 0.f; int np = 0;
    for (int i = tid; i < NB2; i += 256) {
        pc += pp_posce[b * NB2 + i];
        sl += pp_sl1[b * NB2 + i];
        np += pp_np[b * NB2 + i];
    }
    #pragma unroll
    for (int s = 32; s >= 1; s >>= 1) {
        pc += __shfl_xor(pc, s, 64);
        sl += __shfl_xor(sl, s, 64);
        np += __shfl_xor(np, s, 64);
    }
    if ((tid & 63) == 0) { s_i[wid] = np; s_f[wid] = pc; s_f2[wid] = sl; }
    __syncthreads();
    if (tid == 0) {
        int n = 0; float fp = 0.f, fs = 0.f;
        #pragma unroll
        for (int k = 0; k < 4; ++k) { n += s_i[k]; fp += s_f[k]; fs += s_f2[k]; }
        n_pos[b] = n; posce_b[b] = fp; sl1_b[b] = fs;
        s_bcast = n;
        int K0 = 3 * (n > 1 ? n : 1);
        if (K0 > PP) K0 = PP;
        s_sel = 0u; s_krem = K0;
    }
    __syncthreads();
    np = s_bcast;
    int K = 3 * (np > 1 ? np : 1);
    if (K > PP) K = PP;
    // ---- radix select over ceneg[b] (L2/L3-hot): exact bits of K-th largest ----
    const float4* src = (const float4*)(ceneg + (size_t)b * PP);  // PP/4 = 2183
    #pragma unroll
    for (int s = 24; s >= 0; s -= 8) {
        for (int i = tid; i < 4 * 256; i += 256) ((int*)hist)[i] = 0;
        __syncthreads();
        unsigned pref = s_sel; int krem = s_krem;
        int hs = s + 8;
        unsigned prefhi = (hs >= 32) ? 0u : (pref >> (hs & 31));
        for (int i = tid; i < PP / 4; i += 256) {
            float4 q = src[i];
            float vals[4] = {q.x, q.y, q.z, q.w};
            #pragma unroll
            for (int c4 = 0; c4 < 4; ++c4) {
                unsigned bts = __float_as_uint(vals[c4]);
                bool ok = (hs >= 32) || ((bts >> (hs & 31)) == prefhi);
                if (ok) atomicAdd(&hist[wid][(bts >> s) & 255], 1);
            }
        }
        __syncthreads();
        {
            int t = hist[0][tid] + hist[1][tid] + hist[2][tid] + hist[3][tid];
            hsum[tid] = t;
        }
        __syncthreads();
        if (tid < 64) {
            int ln = tid;
            int cum = 0;
            for (int c = 3; c >= 0; --c) {
                int h = hsum[c * 64 + ln];
                int suff = h;                      // descending suffix-sum within chunk
                #pragma unroll
                for (int off = 1; off < 64; off <<= 1) {
                    int t = __shfl_down(suff, off);
                    if (ln + off < 64) suff += t;
                }
                int ctot = __shfl(suff, 0);        // total of this chunk
                if (cum + ctot >= krem) {          // K-th bin is in this chunk
                    unsigned long long m = __ballot(cum + suff >= krem);
                    int l = 63 - __builtin_clzll(m);   // largest bin idx satisfying
                    int suffl = __shfl(suff, l);
                    int hl = __shfl(h, l);
                    if (ln == 0) {
                        s_sel = pref | ((unsigned)(c * 64 + l) << s);
                        s_krem = krem - (cum + suffl - hl);  // rank within chosen bin
                    }
                    break;
                }
                cum += ctot;
            }
        }
        __syncthreads();
    }
    float vk = __uint_as_float(s_sel);   // exact K-th largest value
    // ---- sum of top-K (ties at vk handled exactly) ----
    float sm = 0.f; int cg = 0;
    for (int i = tid; i < PP / 4; i += 256) {
        float4 q = src[i];
        if (q.x > vk) { sm += q.x; cg++; }
        if (q.y > vk) { sm += q.y; cg++; }
        if (q.z > vk) { sm += q.z; cg++; }
        if (q.w > vk) { sm += q.w; cg++; }
    }
    #pragma unroll
    for (int s = 32; s >= 1; s >>= 1) {
        sm += __shfl_xor(sm, s, 64);
        cg += __shfl_xor(cg, s, 64);
    }
    if ((tid & 63) == 0) { s_f[wid] = sm; s_i[wid] = cg; }
    __syncthreads();
    if (tid == 0) {
        float S = 0.f; int CG = 0;
        #pragma unroll
        for (int k = 0; k < 4; ++k) { S += s_f[k]; CG += s_i[k]; }
        hard[b] = S + (float)(K - CG) * vk;
    }
    // ---- fused final: globally-last image-block folds the 64 per-image results ----
    __threadfence();
    __shared__ int s_fin;
    if (tid == 0) s_fin = (atomicAdd(done, 1) == BB - 1) ? 1 : 0;
    __syncthreads();
    if (s_fin) {
        __threadfence();                    // acquire other blocks' writes
        if (tid < 64) {
            int t = tid;                    // BB == 64 == one wave
            int np2 = n_pos[t];
            float h2 = hard[t], pc2 = posce_b[t], sl2 = sl1_b[t];
            float cl = (float)(np2 > 1 ? np2 : 1);
            int tp = np2; float hs2 = h2; float cls = cl;
            #pragma unroll
            for (int sft = 32; sft >= 1; sft >>= 1) {
                tp  += __shfl_xor(tp, sft, 64);
                hs2 += __shfl_xor(hs2, sft, 64);
                cls += __shfl_xor(cls, sft, 64);
                pc2 += __shfl_xor(pc2, sft, 64);
                sl2 += __shfl_xor(sl2, sft, 64);
            }
            if (t == 0) {
                float conf = (hs2 + pc2) / cls;
                float loc = 0.f;
                if (tp > 0) {
                    int den = tp * 4; if (den < 1) den = 1;
                    loc = sl2 / (float)den;
                }
                out[0] = conf + loc;
            }
        }
    }
}

extern "C" void kernel_launch(void* const* d_in, const int* in_sizes, int n_in,
                              void* d_out, int out_size, void* d_ws, size_t ws_size,
                              hipStream_t stream)
{
    const float* pred_locs   = (const float*)d_in[0];
    const float* pred_scores = (const float*)d_in[1];
    const float* gt_boxes    = (const float*)d_in[2];
    const int*   gt_labels   = (const int*)d_in[3];
    const float* priors      = (const float*)d_in[4];

    char* ws = (char*)d_ws;
    const size_t npf = (size_t)BB * PP;          // 558,848
    size_t off = 0;
    int*   olab  = (int*)  (ws + off); off += 4 * npf;
    float* ceneg = (float*)(ws + off); off += 4 * npf;   // 16B-aligned (npf*4 % 16 == 0)
    unsigned long long* part = (unsigned long long*)(ws + off); off += 8 * (size_t)BB * NBM * OO;
    float* pp_posce = (float*)(ws + off); off += 4 * (size_t)BB * NB2;
    float* pp_sl1   = (float*)(ws + off); off += 4 * (size_t)BB * NB2;
    int*   pp_np    = (int*)  (ws + off); off += 4 * (size_t)BB * NB2;
    float* posce_b  = (float*)(ws + off); off += 4 * BB;
    float* sl1_b    = (float*)(ws + off); off += 4 * BB;
    int*   n_pos    = (int*)  (ws + off); off += 4 * BB;
    float* hard     = (float*)(ws + off); off += 4 * BB;
    int*   imgcnt   = (int*)  (ws + off); off += 4 * BB;
    int*   done     = (int*)  (ws + off); off += 4;
    // no memset needed: part/pp_* fully written before read; imgcnt/done zeroed by k_force
    // (k_force precedes k_ce in-stream)

    dim3 gM(NBM, BB);
    k_match<<<gM, 256, 0, stream>>>(gt_boxes, gt_labels, (const float4*)priors, olab, part);

    k_force<<<BB, 64, 0, stream>>>(part, gt_labels, olab, imgcnt, done);

    dim3 gB(NB2, BB);
    k_ce<<<gB, 256, 0, stream>>>(pred_scores, (const float4*)pred_locs, gt_boxes,
                                 (const float4*)priors, olab, ceneg,
                                 pp_posce, pp_sl1, pp_np,
                                 hard, posce_b, sl1_b, n_pos,
                                 imgcnt, done, (float*)d_out);
}

// Round 3
// 1549.580 us; speedup vs baseline: 1.6429x; 1.6429x over previous
//
#include <hip/hip_runtime.h>
#include <cstdint>
#include <cstddef>

#define BB 64
#define PP 8732
#define OO 32
#define CC 81
#define NR 64     // rows (priors) per k_ce block
#define NB3 137   // ceil(8732/64); 136 full blocks + one 28-row tail

// ---------- kernel 1: per-object best prior (global argmax over P), 1 block/image ----------
__global__ __launch_bounds__(1024) void k_prep(
    const float* __restrict__ gt_boxes,      // [B,O,4] coco pixel
    const float4* __restrict__ priors,       // [P] cxcy
    int* __restrict__ pfo,                   // [B,O] best prior per object
    int* __restrict__ done)
{
    int b = blockIdx.x, t = threadIdx.x;
    if (b == 0 && t == 0) *done = 0;         // counter for k_topk's fused final
    __shared__ float bx1[OO], by1[OO], bx2[OO], by2[OO], bar[OO];
    __shared__ unsigned long long wred[16][OO];
    if (t < OO) {
        const float* g = gt_boxes + ((size_t)b * OO + t) * 4;
        float x1 = g[0] / 224.0f, y1 = g[1] / 224.0f;
        float x2 = (g[0] + g[2]) / 224.0f, y2 = (g[1] + g[3]) / 224.0f;
        bx1[t] = x1; by1[t] = y1; bx2[t] = x2; by2[t] = y2;
        bar[t] = (x2 - x1) * (y2 - y1);
    }
    __syncthreads();
    float best[OO]; int bp[OO];
    #pragma unroll
    for (int o = 0; o < OO; ++o) { best[o] = -1.0f; bp[o] = 0; }
    for (int p = t; p < PP; p += 1024) {      // every thread sees >=8 priors (ascending)
        float4 pr = priors[p];
        float px1 = pr.x - pr.z * 0.5f, py1 = pr.y - pr.w * 0.5f;
        float px2 = pr.x + pr.z * 0.5f, py2 = pr.y + pr.w * 0.5f;
        float parea = (px2 - px1) * (py2 - py1);
        #pragma unroll
        for (int o = 0; o < OO; ++o) {
            float lx = fmaxf(bx1[o], px1), ly = fmaxf(by1[o], py1);
            float rx = fminf(bx2[o], px2), ry = fminf(by2[o], py2);
            float w = fmaxf(rx - lx, 0.0f), h = fmaxf(ry - ly, 0.0f);
            float inter = w * h;
            float iou = inter / (bar[o] + parea - inter);
            if (iou > best[o]) { best[o] = iou; bp[o] = p; }  // strict > : smallest p on ties
        }
    }
    int lane = t & 63, wv = t >> 6;
    #pragma unroll
    for (int o = 0; o < OO; ++o) {
        unsigned long long v = ((unsigned long long)__float_as_uint(best[o]) << 32)
                             | (unsigned long long)(0xFFFFFFFFu - (unsigned)bp[o]);
        #pragma unroll
        for (int s = 32; s >= 1; s >>= 1) {
            unsigned long long u = __shfl_xor(v, s, 64);
            if (u > v) v = u;                 // max packed: larger iou, then smaller p
        }
        if (lane == 0) wred[wv][o] = v;
    }
    __syncthreads();
    if (t < OO) {
        unsigned long long m = wred[0][t];
        #pragma unroll
        for (int w = 1; w < 16; ++w) if (wred[w][t] > m) m = wred[w][t];
        pfo[b * OO + t] = (int)(0xFFFFFFFFu - (unsigned)(m & 0xFFFFFFFFull));
    }
}

// ---------- kernel 2: fused match + CE + loc loss; 64 rows/block, LDS-staged scores ----------
__global__ __launch_bounds__(256) void k_ce(
    const float* __restrict__ scores,        // [B,P,C]
    const float4* __restrict__ pred_locs,
    const float* __restrict__ gt_boxes,
    const int* __restrict__ gt_labels,
    const float4* __restrict__ priors,
    const int* __restrict__ pfo,
    float* __restrict__ ceneg,
    float* __restrict__ pp_posce, float* __restrict__ pp_sl1,
    int* __restrict__ pp_np)
{
    int b = blockIdx.y, tid = threadIdx.x;
    int row0 = blockIdx.x * NR;
    int nrows = PP - row0; if (nrows > NR) nrows = NR;   // 64 or 28 (tail)

    __shared__ float sv[NR * CC];            // 20736 B staged scores
    __shared__ float4 s_pr[NR];
    __shared__ float bx1[OO], by1[OO], bx2[OO], by2[OO], bar[OO];
    __shared__ int s_lab[OO];
    __shared__ int s_force[NR];
    __shared__ float s_cn[NR];
    __shared__ float s_posce, s_sl1;
    __shared__ int s_np;

    if (tid == 0) { s_posce = 0.f; s_sl1 = 0.f; s_np = 0; }
    if (tid < OO) {
        const float* g = gt_boxes + ((size_t)b * OO + tid) * 4;
        float x1 = g[0] / 224.0f, y1 = g[1] / 224.0f;
        float x2 = (g[0] + g[2]) / 224.0f, y2 = (g[1] + g[3]) / 224.0f;
        bx1[tid] = x1; by1[tid] = y1; bx2[tid] = x2; by2[tid] = y2;
        bar[tid] = (x2 - x1) * (y2 - y1);
        s_lab[tid] = gt_labels[b * OO + tid];
    }
    if (tid < NR) {
        s_force[tid] = -1;
        if (row0 + tid < PP) s_pr[tid] = priors[row0 + tid];
    }
    __syncthreads();
    if (tid == 0) {                           // ascending o = numpy last-wins on collisions
        #pragma unroll
        for (int o = 0; o < OO; ++o) {
            int rp = pfo[b * OO + o] - row0;
            if (rp >= 0 && rp < nrows) s_force[rp] = o;
        }
    }
    // stage scores: exact float4 count, 16B-aligned for every block (nrows*81 % 4 == 0)
    {
        const float4* src4 = (const float4*)(scores + ((size_t)b * PP + row0) * CC);
        int nvec = nrows * CC / 4;            // 1296 or 567
        float4* dst = (float4*)sv;
        for (int i = tid; i < nvec; i += 256) dst[i] = src4[i];
    }
    __syncthreads();

    int g = tid >> 4, lane = tid & 15;        // 16 groups x 16 lanes; group g: rows g+16j
    #pragma unroll
    for (int j = 0; j < 4; ++j) {
        int r = g + 16 * j;
        if (r < nrows) {                      // uniform across the 16-lane group
            float4 pq = s_pr[r];
            float px1 = pq.x - pq.z * 0.5f, py1 = pq.y - pq.w * 0.5f;
            float px2 = pq.x + pq.z * 0.5f, py2 = pq.y + pq.w * 0.5f;
            float parea = (px2 - px1) * (py2 - py1);
            // per-prior argmax over 32 objects: 2 objects/lane + 4-step butterfly
            float bi; int bo;
            {
                int o1 = lane, o2 = lane + 16;
                float lx = fmaxf(bx1[o1], px1), ly = fmaxf(by1[o1], py1);
                float rx = fminf(bx2[o1], px2), ry = fminf(by2[o1], py2);
                float w1 = fmaxf(rx - lx, 0.0f), h1 = fmaxf(ry - ly, 0.0f);
                float in1 = w1 * h1;
                float i1 = in1 / (bar[o1] + parea - in1);
                lx = fmaxf(bx1[o2], px1); ly = fmaxf(by1[o2], py1);
                rx = fminf(bx2[o2], px2); ry = fminf(by2[o2], py2);
                float w2 = fmaxf(rx - lx, 0.0f), h2 = fmaxf(ry - ly, 0.0f);
                float in2 = w2 * h2;
                float i2 = in2 / (bar[o2] + parea - in2);
                bi = i1; bo = o1;
                if (i2 > bi) { bi = i2; bo = o2; }    // strict > : smaller o on ties
                unsigned long long pk = ((unsigned long long)__float_as_uint(bi) << 32)
                                      | (unsigned long long)(0xFFFFFFFFu - (unsigned)bo);
                #pragma unroll
                for (int s = 8; s >= 1; s >>= 1) {
                    unsigned long long u = __shfl_xor(pk, s, 16);
                    if (u > pk) pk = u;
                }
                bi = __uint_as_float((unsigned)(pk >> 32));
                bo = (int)(0xFFFFFFFFu - (unsigned)(pk & 0xFFFFFFFFull));
            }
            int fo = s_force[r];
            int lab, ob;
            if (fo >= 0) { ob = fo; lab = s_lab[fo]; }           // forced positive (ovl=1.0)
            else         { ob = bo; lab = (bi < 0.5f) ? 0 : s_lab[bo]; }
            // CE from LDS
            float se = 0.f, xl = 0.f;
            #pragma unroll
            for (int k = 0; k < 6; ++k) {
                int c = lane + 16 * k;
                if (c < CC) {
                    float vv = sv[r * CC + c];
                    se += __expf(vv);
                    if (c == lab) xl = vv;
                }
            }
            #pragma unroll
            for (int s = 8; s >= 1; s >>= 1) {
                se += __shfl_xor(se, s, 16);
                xl += __shfl_xor(xl, s, 16);
            }
            if (lane == 0) {
                float ce = fmaxf(__logf(se) - xl, 0.0f);   // >=0 (radix select assumes)
                float cn = ce;
                if (lab != 0) {
                    cn = 0.f;
                    float4 pl = pred_locs[(size_t)b * PP + row0 + r];
                    float x1 = bx1[ob], y1 = by1[ob], x2 = bx2[ob], y2 = by2[ob];
                    float cx = (x1 + x2) * 0.5f, cy = (y1 + y2) * 0.5f;
                    float w = x2 - x1, h = y2 - y1;
                    float tx = (cx - pq.x) / (pq.z / 10.0f);
                    float ty = (cy - pq.y) / (pq.w / 10.0f);
                    float tw = __logf(w / pq.z) * 5.0f;
                    float th = __logf(h / pq.w) * 5.0f;
                    float d0 = fabsf(pl.x - tx), d1 = fabsf(pl.y - ty);
                    float d2 = fabsf(pl.z - tw), d3 = fabsf(pl.w - th);
                    float sl = (d0 < 1.f ? 0.5f * d0 * d0 : d0 - 0.5f)
                             + (d1 < 1.f ? 0.5f * d1 * d1 : d1 - 0.5f)
                             + (d2 < 1.f ? 0.5f * d2 * d2 : d2 - 0.5f)
                             + (d3 < 1.f ? 0.5f * d3 * d3 : d3 - 0.5f);
                    atomicAdd(&s_posce, ce);
                    atomicAdd(&s_sl1, sl);
                    atomicAdd(&s_np, 1);
                }
                s_cn[r] = cn;
            }
        }
    }
    __syncthreads();
    if (tid < nrows) ceneg[(size_t)b * PP + row0 + tid] = s_cn[tid];
    if (tid == 0) {
        int slot = b * NB3 + blockIdx.x;      // dedicated slot: zero global atomics
        pp_posce[slot] = s_posce;
        pp_sl1[slot]   = s_sl1;
        pp_np[slot]    = s_np;
    }
}

// ---------- kernel 3: fold partials + exact top-K via 4-pass radix select + fused final ----------
__global__ __launch_bounds__(512) void k_topk(
    const float* __restrict__ ceneg,
    const float* __restrict__ pp_posce, const float* __restrict__ pp_sl1,
    const int* __restrict__ pp_np,
    float* __restrict__ hard, float* __restrict__ posce_b,
    float* __restrict__ sl1_b, int* __restrict__ n_pos,
    int* __restrict__ done, float* __restrict__ out)
{
    int b = blockIdx.x, tid = threadIdx.x;
    __shared__ float4 sv4[PP / 4];           // 8732/4 = 2183 (34928 B)
    __shared__ int hist[8][256];             // per-wave histograms
    __shared__ int hsum[256];
    __shared__ int s_i[8];
    __shared__ float s_f[8], s_f2[8];
    __shared__ int s_bcast;
    __shared__ unsigned s_sel;
    __shared__ int s_krem;
    __shared__ int s_last;
    // fold per-block partials for this image
    float pc = 0.f, sl = 0.f; int np = 0;
    for (int i = tid; i < NB3; i += 512) {
        pc += pp_posce[b * NB3 + i];
        sl += pp_sl1[b * NB3 + i];
        np += pp_np[b * NB3 + i];
    }
    #pragma unroll
    for (int s = 32; s >= 1; s >>= 1) {
        pc += __shfl_xor(pc, s, 64);
        sl += __shfl_xor(sl, s, 64);
        np += __shfl_xor(np, s, 64);
    }
    int wid = tid >> 6;
    if ((tid & 63) == 0) { s_i[wid] = np; s_f[wid] = pc; s_f2[wid] = sl; }
    // stage ce_neg into LDS (float4)
    const float4* src = (const float4*)(ceneg + (size_t)b * PP);
    for (int i = tid; i < PP / 4; i += 512) sv4[i] = src[i];
    __syncthreads();
    if (tid == 0) {
        int n = 0; float fp = 0.f, fs = 0.f;
        #pragma unroll
        for (int k = 0; k < 8; ++k) { n += s_i[k]; fp += s_f[k]; fs += s_f2[k]; }
        n_pos[b] = n; posce_b[b] = fp; sl1_b[b] = fs;
        s_bcast = n;
        int K0 = 3 * (n > 1 ? n : 1);
        if (K0 > PP) K0 = PP;
        s_sel = 0u; s_krem = K0;
    }
    __syncthreads();
    np = s_bcast;
    int K = 3 * (np > 1 ? np : 1);
    if (K > PP) K = PP;
    // ---- radix select: exact bits of K-th largest (values >= 0 so uint order == float order)
    #pragma unroll
    for (int s = 24; s >= 0; s -= 8) {
        for (int i = tid; i < 8 * 256; i += 512) ((int*)hist)[i] = 0;
        __syncthreads();
        unsigned pref = s_sel; int krem = s_krem;
        int hs = s + 8;
        unsigned prefhi = (hs >= 32) ? 0u : (pref >> (hs & 31));
        for (int i = tid; i < PP / 4; i += 512) {
            float4 q = sv4[i];
            float vals[4] = {q.x, q.y, q.z, q.w};
            #pragma unroll
            for (int c4 = 0; c4 < 4; ++c4) {
                unsigned bts = __float_as_uint(vals[c4]);
                bool ok = (hs >= 32) || ((bts >> (hs & 31)) == prefhi);
                if (ok) atomicAdd(&hist[wid][(bts >> s) & 255], 1);
            }
        }
        __syncthreads();
        if (tid < 256) {
            int t = 0;
            #pragma unroll
            for (int k = 0; k < 8; ++k) t += hist[k][tid];
            hsum[tid] = t;
        }
        __syncthreads();
        if (tid < 64) {
            int ln = tid;
            int cum = 0;
            for (int c = 3; c >= 0; --c) {
                int h = hsum[c * 64 + ln];
                int suff = h;                      // descending suffix-sum within chunk
                #pragma unroll
                for (int off = 1; off < 64; off <<= 1) {
                    int t = __shfl_down(suff, off);
                    if (ln + off < 64) suff += t;
                }
                int ctot = __shfl(suff, 0);        // total of this chunk
                if (cum + ctot >= krem) {          // K-th bin is in this chunk
                    unsigned long long m = __ballot(cum + suff >= krem);
                    int l = 63 - __builtin_clzll(m);
                    int suffl = __shfl(suff, l);
                    int hl = __shfl(h, l);
                    if (ln == 0) {
                        s_sel = pref | ((unsigned)(c * 64 + l) << s);
                        s_krem = krem - (cum + suffl - hl);
                    }
                    break;
                }
                cum += ctot;
            }
        }
        __syncthreads();
    }
    float vk = __uint_as_float(s_sel);   // exact K-th largest value
    // ---- sum of top-K (ties at vk handled exactly)
    float sm = 0.f; int cg = 0;
    for (int i = tid; i < PP / 4; i += 512) {
        float4 q = sv4[i];
        if (q.x > vk) { sm += q.x; cg++; }
        if (q.y > vk) { sm += q.y; cg++; }
        if (q.z > vk) { sm += q.z; cg++; }
        if (q.w > vk) { sm += q.w; cg++; }
    }
    #pragma unroll
    for (int s = 32; s >= 1; s >>= 1) {
        sm += __shfl_xor(sm, s, 64);
        cg += __shfl_xor(cg, s, 64);
    }
    if ((tid & 63) == 0) { s_f[wid] = sm; s_i[wid] = cg; }
    __syncthreads();
    if (tid == 0) {
        float S = 0.f; int CG = 0;
        #pragma unroll
        for (int k = 0; k < 8; ++k) { S += s_f[k]; CG += s_i[k]; }
        hard[b] = S + (float)(K - CG) * vk;
    }
    // ---- fused final: last of the 64 blocks folds per-image results (fence in 64 blocks only)
    __threadfence();
    if (tid == 0) s_last = (atomicAdd(done, 1) == BB - 1) ? 1 : 0;
    __syncthreads();
    if (s_last) {
        __threadfence();
        if (tid < 64) {
            int t = tid;                    // BB == 64 == one wave
            int np2 = n_pos[t];
            float h2 = hard[t], pc2 = posce_b[t], sl2 = sl1_b[t];
            float cl = (float)(np2 > 1 ? np2 : 1);
            int tp = np2; float hs2 = h2; float cls = cl;
            #pragma unroll
            for (int sft = 32; sft >= 1; sft >>= 1) {
                tp  += __shfl_xor(tp, sft, 64);
                hs2 += __shfl_xor(hs2, sft, 64);
                cls += __shfl_xor(cls, sft, 64);
                pc2 += __shfl_xor(pc2, sft, 64);
                sl2 += __shfl_xor(sl2, sft, 64);
            }
            if (t == 0) {
                float conf = (hs2 + pc2) / cls;
                float loc = 0.f;
                if (tp > 0) {
                    int den = tp * 4; if (den < 1) den = 1;
                    loc = sl2 / (float)den;
                }
                out[0] = conf + loc;
            }
        }
    }
}

extern "C" void kernel_launch(void* const* d_in, const int* in_sizes, int n_in,
                              void* d_out, int out_size, void* d_ws, size_t ws_size,
                              hipStream_t stream)
{
    const float* pred_locs   = (const float*)d_in[0];
    const float* pred_scores = (const float*)d_in[1];
    const float* gt_boxes    = (const float*)d_in[2];
    const int*   gt_labels   = (const int*)d_in[3];
    const float* priors      = (const float*)d_in[4];

    char* ws = (char*)d_ws;
    const size_t npf = (size_t)BB * PP;          // 558,848
    size_t off = 0;
    float* ceneg = (float*)(ws + off); off += 4 * npf;   // 16B-aligned
    int*   pfo   = (int*)  (ws + off); off += 4 * (size_t)BB * OO;
    float* pp_posce = (float*)(ws + off); off += 4 * (size_t)BB * NB3;
    float* pp_sl1   = (float*)(ws + off); off += 4 * (size_t)BB * NB3;
    int*   pp_np    = (int*)  (ws + off); off += 4 * (size_t)BB * NB3;
    float* posce_b  = (float*)(ws + off); off += 4 * BB;
    float* sl1_b    = (float*)(ws + off); off += 4 * BB;
    int*   n_pos    = (int*)  (ws + off); off += 4 * BB;
    float* hard     = (float*)(ws + off); off += 4 * BB;
    int*   done     = (int*)  (ws + off); off += 4;
    // no memset needed: every buffer is fully written before it is read each iteration
    // (done zeroed by k_prep, which precedes k_topk in-stream)

    k_prep<<<BB, 1024, 0, stream>>>(gt_boxes, (const float4*)priors, pfo, done);

    dim3 gB(NB3, BB);
    k_ce<<<gB, 256, 0, stream>>>(pred_scores, (const float4*)pred_locs, gt_boxes, gt_labels,
                                 (const float4*)priors, pfo, ceneg,
                                 pp_posce, pp_sl1, pp_np);

    k_topk<<<BB, 512, 0, stream>>>(ceneg, pp_posce, pp_sl1, pp_np,
                                   hard, posce_b, sl1_b, n_pos, done, (float*)d_out);
}

// Round 4
// 378.987 us; speedup vs baseline: 6.7173x; 4.0887x over previous
//
#include <hip/hip_runtime.h>
#include <cstdint>
#include <cstddef>

#define BB 64
#define PP 8732
#define OO 32
#define CC 81
#define NR 64     // rows (priors) per k_ce block
#define NB3 137   // ceil(8732/64); 136 full blocks + one 28-row tail

// ---------- kernel 1: per-object best prior (global argmax over P), 1 block/image ----------
// thread t -> (object o = t>>5, slice s = t&31). One (iou, prior) pair of state per thread:
// no per-thread arrays, no scratch spill (round-3 lesson: best[32]/bp[32] spilled -> 2.1 GB HBM).
__global__ __launch_bounds__(1024) void k_prep(
    const float* __restrict__ gt_boxes,      // [B,O,4] coco pixel
    const float4* __restrict__ priors,       // [P] cxcy
    int* __restrict__ pfo,                   // [B,O] best prior per object
    int* __restrict__ done)
{
    int b = blockIdx.x, t = threadIdx.x;
    if (b == 0 && t == 0) *done = 0;         // counter for k_topk's fused final
    int o = t >> 5, s = t & 31;
    __shared__ float4 s_pr[1024];            // 16 KB prior chunk
    const float* g = gt_boxes + ((size_t)b * OO + o) * 4;
    float x1 = g[0] / 224.0f, y1 = g[1] / 224.0f;
    float x2 = (g[0] + g[2]) / 224.0f, y2 = (g[1] + g[3]) / 224.0f;
    float area = (x2 - x1) * (y2 - y1);
    float best = -1.0f; int bp = 0;
    for (int base = 0; base < PP; base += 1024) {
        int idx = base + t;
        if (idx < PP) s_pr[t] = priors[idx];
        __syncthreads();
        int lim = PP - base; if (lim > 1024) lim = 1024;
        for (int j = s; j < lim; j += 32) {   // ascending p: strict > keeps smallest p on ties
            float4 pr = s_pr[j];
            float px1 = pr.x - pr.z * 0.5f, py1 = pr.y - pr.w * 0.5f;
            float px2 = pr.x + pr.z * 0.5f, py2 = pr.y + pr.w * 0.5f;
            float parea = (px2 - px1) * (py2 - py1);
            float lx = fmaxf(x1, px1), ly = fmaxf(y1, py1);
            float rx = fminf(x2, px2), ry = fminf(y2, py2);
            float w = fmaxf(rx - lx, 0.0f), h = fmaxf(ry - ly, 0.0f);
            float inter = w * h;
            float iou = inter / (area + parea - inter);
            if (iou > best) { best = iou; bp = base + j; }
        }
        __syncthreads();
    }
    // packed (iou, ~p) max across the 32 slices of this object (one 32-lane group)
    unsigned long long v = ((unsigned long long)__float_as_uint(best) << 32)
                         | (unsigned long long)(0xFFFFFFFFu - (unsigned)bp);
    #pragma unroll
    for (int sh = 16; sh >= 1; sh >>= 1) {
        unsigned long long u = __shfl_xor(v, sh, 32);
        if (u > v) v = u;                    // larger iou, then smaller p
    }
    if (s == 0) pfo[b * OO + o] = (int)(0xFFFFFFFFu - (unsigned)(v & 0xFFFFFFFFull));
}

// ---------- kernel 2: fused match + CE + loc loss; 64 rows/block, LDS-staged scores ----------
__global__ __launch_bounds__(256) void k_ce(
    const float* __restrict__ scores,        // [B,P,C]
    const float4* __restrict__ pred_locs,
    const float* __restrict__ gt_boxes,
    const int* __restrict__ gt_labels,
    const float4* __restrict__ priors,
    const int* __restrict__ pfo,
    float* __restrict__ ceneg,
    float* __restrict__ pp_posce, float* __restrict__ pp_sl1,
    int* __restrict__ pp_np)
{
    int b = blockIdx.y, tid = threadIdx.x;
    int row0 = blockIdx.x * NR;
    int nrows = PP - row0; if (nrows > NR) nrows = NR;   // 64 or 28 (tail)

    __shared__ float sv[NR * CC];            // 20736 B staged scores
    __shared__ float4 s_pr[NR];
    __shared__ float bx1[OO], by1[OO], bx2[OO], by2[OO], bar[OO];
    __shared__ int s_lab[OO];
    __shared__ int s_force[NR];
    __shared__ float s_cn[NR];
    __shared__ float s_posce, s_sl1;
    __shared__ int s_np;

    if (tid == 0) { s_posce = 0.f; s_sl1 = 0.f; s_np = 0; }
    if (tid < OO) {
        const float* g = gt_boxes + ((size_t)b * OO + tid) * 4;
        float x1 = g[0] / 224.0f, y1 = g[1] / 224.0f;
        float x2 = (g[0] + g[2]) / 224.0f, y2 = (g[1] + g[3]) / 224.0f;
        bx1[tid] = x1; by1[tid] = y1; bx2[tid] = x2; by2[tid] = y2;
        bar[tid] = (x2 - x1) * (y2 - y1);
        s_lab[tid] = gt_labels[b * OO + tid];
    }
    if (tid < NR) {
        s_force[tid] = -1;
        if (row0 + tid < PP) s_pr[tid] = priors[row0 + tid];
    }
    __syncthreads();
    if (tid == 0) {                           // ascending o = numpy last-wins on collisions
        #pragma unroll
        for (int o = 0; o < OO; ++o) {
            int rp = pfo[b * OO + o] - row0;
            if (rp >= 0 && rp < nrows) s_force[rp] = o;
        }
    }
    // stage scores: exact float4 count, 16B-aligned for every block (nrows*81 % 4 == 0)
    {
        const float4* src4 = (const float4*)(scores + ((size_t)b * PP + row0) * CC);
        int nvec = nrows * CC / 4;            // 1296 or 567
        float4* dst = (float4*)sv;
        for (int i = tid; i < nvec; i += 256) dst[i] = src4[i];
    }
    __syncthreads();

    int g = tid >> 4, lane = tid & 15;        // 16 groups x 16 lanes; group g: rows g+16j
    #pragma unroll
    for (int j = 0; j < 4; ++j) {
        int r = g + 16 * j;
        if (r < nrows) {                      // uniform across the 16-lane group
            float4 pq = s_pr[r];
            float px1 = pq.x - pq.z * 0.5f, py1 = pq.y - pq.w * 0.5f;
            float px2 = pq.x + pq.z * 0.5f, py2 = pq.y + pq.w * 0.5f;
            float parea = (px2 - px1) * (py2 - py1);
            // per-prior argmax over 32 objects: 2 objects/lane + 4-step butterfly
            float bi; int bo;
            {
                int o1 = lane, o2 = lane + 16;
                float lx = fmaxf(bx1[o1], px1), ly = fmaxf(by1[o1], py1);
                float rx = fminf(bx2[o1], px2), ry = fminf(by2[o1], py2);
                float w1 = fmaxf(rx - lx, 0.0f), h1 = fmaxf(ry - ly, 0.0f);
                float in1 = w1 * h1;
                float i1 = in1 / (bar[o1] + parea - in1);
                lx = fmaxf(bx1[o2], px1); ly = fmaxf(by1[o2], py1);
                rx = fminf(bx2[o2], px2); ry = fminf(by2[o2], py2);
                float w2 = fmaxf(rx - lx, 0.0f), h2 = fmaxf(ry - ly, 0.0f);
                float in2 = w2 * h2;
                float i2 = in2 / (bar[o2] + parea - in2);
                bi = i1; bo = o1;
                if (i2 > bi) { bi = i2; bo = o2; }    // strict > : smaller o on ties
                unsigned long long pk = ((unsigned long long)__float_as_uint(bi) << 32)
                                      | (unsigned long long)(0xFFFFFFFFu - (unsigned)bo);
                #pragma unroll
                for (int s = 8; s >= 1; s >>= 1) {
                    unsigned long long u = __shfl_xor(pk, s, 16);
                    if (u > pk) pk = u;
                }
                bi = __uint_as_float((unsigned)(pk >> 32));
                bo = (int)(0xFFFFFFFFu - (unsigned)(pk & 0xFFFFFFFFull));
            }
            int fo = s_force[r];
            int lab, ob;
            if (fo >= 0) { ob = fo; lab = s_lab[fo]; }           // forced positive (ovl=1.0)
            else         { ob = bo; lab = (bi < 0.5f) ? 0 : s_lab[bo]; }
            // CE from LDS
            float se = 0.f, xl = 0.f;
            #pragma unroll
            for (int k = 0; k < 6; ++k) {
                int c = lane + 16 * k;
                if (c < CC) {
                    float vv = sv[r * CC + c];
                    se += __expf(vv);
                    if (c == lab) xl = vv;
                }
            }
            #pragma unroll
            for (int s = 8; s >= 1; s >>= 1) {
                se += __shfl_xor(se, s, 16);
                xl += __shfl_xor(xl, s, 16);
            }
            if (lane == 0) {
                float ce = fmaxf(__logf(se) - xl, 0.0f);   // >=0 (radix select assumes)
                float cn = ce;
                if (lab != 0) {
                    cn = 0.f;
                    float4 pl = pred_locs[(size_t)b * PP + row0 + r];
                    float x1 = bx1[ob], y1 = by1[ob], x2 = bx2[ob], y2 = by2[ob];
                    float cx = (x1 + x2) * 0.5f, cy = (y1 + y2) * 0.5f;
                    float w = x2 - x1, h = y2 - y1;
                    float tx = (cx - pq.x) / (pq.z / 10.0f);
                    float ty = (cy - pq.y) / (pq.w / 10.0f);
                    float tw = __logf(w / pq.z) * 5.0f;
                    float th = __logf(h / pq.w) * 5.0f;
                    float d0 = fabsf(pl.x - tx), d1 = fabsf(pl.y - ty);
                    float d2 = fabsf(pl.z - tw), d3 = fabsf(pl.w - th);
                    float sl = (d0 < 1.f ? 0.5f * d0 * d0 : d0 - 0.5f)
                             + (d1 < 1.f ? 0.5f * d1 * d1 : d1 - 0.5f)
                             + (d2 < 1.f ? 0.5f * d2 * d2 : d2 - 0.5f)
                             + (d3 < 1.f ? 0.5f * d3 * d3 : d3 - 0.5f);
                    atomicAdd(&s_posce, ce);
                    atomicAdd(&s_sl1, sl);
                    atomicAdd(&s_np, 1);
                }
                s_cn[r] = cn;
            }
        }
    }
    __syncthreads();
    if (tid < nrows) ceneg[(size_t)b * PP + row0 + tid] = s_cn[tid];
    if (tid == 0) {
        int slot = b * NB3 + blockIdx.x;      // dedicated slot: zero global atomics
        pp_posce[slot] = s_posce;
        pp_sl1[slot]   = s_sl1;
        pp_np[slot]    = s_np;
    }
}

// ---------- kernel 3: fold partials + exact top-K via 4-pass radix select + fused final ----------
__global__ __launch_bounds__(512) void k_topk(
    const float* __restrict__ ceneg,
    const float* __restrict__ pp_posce, const float* __restrict__ pp_sl1,
    const int* __restrict__ pp_np,
    float* __restrict__ hard, float* __restrict__ posce_b,
    float* __restrict__ sl1_b, int* __restrict__ n_pos,
    int* __restrict__ done, float* __restrict__ out)
{
    int b = blockIdx.x, tid = threadIdx.x;
    __shared__ float4 sv4[PP / 4];           // 8732/4 = 2183 (34928 B)
    __shared__ int hist[8][256];             // per-wave histograms
    __shared__ int hsum[256];
    __shared__ int s_i[8];
    __shared__ float s_f[8], s_f2[8];
    __shared__ int s_bcast;
    __shared__ unsigned s_sel;
    __shared__ int s_krem;
    __shared__ int s_last;
    // fold per-block partials for this image
    float pc = 0.f, sl = 0.f; int np = 0;
    for (int i = tid; i < NB3; i += 512) {
        pc += pp_posce[b * NB3 + i];
        sl += pp_sl1[b * NB3 + i];
        np += pp_np[b * NB3 + i];
    }
    #pragma unroll
    for (int s = 32; s >= 1; s >>= 1) {
        pc += __shfl_xor(pc, s, 64);
        sl += __shfl_xor(sl, s, 64);
        np += __shfl_xor(np, s, 64);
    }
    int wid = tid >> 6;
    if ((tid & 63) == 0) { s_i[wid] = np; s_f[wid] = pc; s_f2[wid] = sl; }
    // stage ce_neg into LDS (float4)
    const float4* src = (const float4*)(ceneg + (size_t)b * PP);
    for (int i = tid; i < PP / 4; i += 512) sv4[i] = src[i];
    __syncthreads();
    if (tid == 0) {
        int n = 0; float fp = 0.f, fs = 0.f;
        #pragma unroll
        for (int k = 0; k < 8; ++k) { n += s_i[k]; fp += s_f[k]; fs += s_f2[k]; }
        n_pos[b] = n; posce_b[b] = fp; sl1_b[b] = fs;
        s_bcast = n;
        int K0 = 3 * (n > 1 ? n : 1);
        if (K0 > PP) K0 = PP;
        s_sel = 0u; s_krem = K0;
    }
    __syncthreads();
    np = s_bcast;
    int K = 3 * (np > 1 ? np : 1);
    if (K > PP) K = PP;
    // ---- radix select: exact bits of K-th largest (values >= 0 so uint order == float order)
    #pragma unroll
    for (int s = 24; s >= 0; s -= 8) {
        for (int i = tid; i < 8 * 256; i += 512) ((int*)hist)[i] = 0;
        __syncthreads();
        unsigned pref = s_sel; int krem = s_krem;
        int hs = s + 8;
        unsigned prefhi = (hs >= 32) ? 0u : (pref >> (hs & 31));
        for (int i = tid; i < PP / 4; i += 512) {
            float4 q = sv4[i];
            float vals[4] = {q.x, q.y, q.z, q.w};
            #pragma unroll
            for (int c4 = 0; c4 < 4; ++c4) {
                unsigned bts = __float_as_uint(vals[c4]);
                bool ok = (hs >= 32) || ((bts >> (hs & 31)) == prefhi);
                if (ok) atomicAdd(&hist[wid][(bts >> s) & 255], 1);
            }
        }
        __syncthreads();
        if (tid < 256) {
            int t = 0;
            #pragma unroll
            for (int k = 0; k < 8; ++k) t += hist[k][tid];
            hsum[tid] = t;
        }
        __syncthreads();
        if (tid < 64) {
            int ln = tid;
            int cum = 0;
            for (int c = 3; c >= 0; --c) {
                int h = hsum[c * 64 + ln];
                int suff = h;                      // descending suffix-sum within chunk
                #pragma unroll
                for (int off = 1; off < 64; off <<= 1) {
                    int t = __shfl_down(suff, off);
                    if (ln + off < 64) suff += t;
                }
                int ctot = __shfl(suff, 0);        // total of this chunk
                if (cum + ctot >= krem) {          // K-th bin is in this chunk
                    unsigned long long m = __ballot(cum + suff >= krem);
                    int l = 63 - __builtin_clzll(m);
                    int suffl = __shfl(suff, l);
                    int hl = __shfl(h, l);
                    if (ln == 0) {
                        s_sel = pref | ((unsigned)(c * 64 + l) << s);
                        s_krem = krem - (cum + suffl - hl);
                    }
                    break;
                }
                cum += ctot;
            }
        }
        __syncthreads();
    }
    float vk = __uint_as_float(s_sel);   // exact K-th largest value
    // ---- sum of top-K (ties at vk handled exactly)
    float sm = 0.f; int cg = 0;
    for (int i = tid; i < PP / 4; i += 512) {
        float4 q = sv4[i];
        if (q.x > vk) { sm += q.x; cg++; }
        if (q.y > vk) { sm += q.y; cg++; }
        if (q.z > vk) { sm += q.z; cg++; }
        if (q.w > vk) { sm += q.w; cg++; }
    }
    #pragma unroll
    for (int s = 32; s >= 1; s >>= 1) {
        sm += __shfl_xor(sm, s, 64);
        cg += __shfl_xor(cg, s, 64);
    }
    if ((tid & 63) == 0) { s_f[wid] = sm; s_i[wid] = cg; }
    __syncthreads();
    if (tid == 0) {
        float S = 0.f; int CG = 0;
        #pragma unroll
        for (int k = 0; k < 8; ++k) { S += s_f[k]; CG += s_i[k]; }
        hard[b] = S + (float)(K - CG) * vk;
    }
    // ---- fused final: last of the 64 blocks folds per-image results (fence in 64 blocks only)
    __threadfence();
    if (tid == 0) s_last = (atomicAdd(done, 1) == BB - 1) ? 1 : 0;
    __syncthreads();
    if (s_last) {
        __threadfence();
        if (tid < 64) {
            int t = tid;                    // BB == 64 == one wave
            int np2 = n_pos[t];
            float h2 = hard[t], pc2 = posce_b[t], sl2 = sl1_b[t];
            float cl = (float)(np2 > 1 ? np2 : 1);
            int tp = np2; float hs2 = h2; float cls = cl;
            #pragma unroll
            for (int sft = 32; sft >= 1; sft >>= 1) {
                tp  += __shfl_xor(tp, sft, 64);
                hs2 += __shfl_xor(hs2, sft, 64);
                cls += __shfl_xor(cls, sft, 64);
                pc2 += __shfl_xor(pc2, sft, 64);
                sl2 += __shfl_xor(sl2, sft, 64);
            }
            if (t == 0) {
                float conf = (hs2 + pc2) / cls;
                float loc = 0.f;
                if (tp > 0) {
                    int den = tp * 4; if (den < 1) den = 1;
                    loc = sl2 / (float)den;
                }
                out[0] = conf + loc;
            }
        }
    }
}

extern "C" void kernel_launch(void* const* d_in, const int* in_sizes, int n_in,
                              void* d_out, int out_size, void* d_ws, size_t ws_size,
                              hipStream_t stream)
{
    const float* pred_locs   = (const float*)d_in[0];
    const float* pred_scores = (const float*)d_in[1];
    const float* gt_boxes    = (const float*)d_in[2];
    const int*   gt_labels   = (const int*)d_in[3];
    const float* priors      = (const float*)d_in[4];

    char* ws = (char*)d_ws;
    const size_t npf = (size_t)BB * PP;          // 558,848
    size_t off = 0;
    float* ceneg = (float*)(ws + off); off += 4 * npf;   // 16B-aligned
    int*   pfo   = (int*)  (ws + off); off += 4 * (size_t)BB * OO;
    float* pp_posce = (float*)(ws + off); off += 4 * (size_t)BB * NB3;
    float* pp_sl1   = (float*)(ws + off); off += 4 * (size_t)BB * NB3;
    int*   pp_np    = (int*)  (ws + off); off += 4 * (size_t)BB * NB3;
    float* posce_b  = (float*)(ws + off); off += 4 * BB;
    float* sl1_b    = (float*)(ws + off); off += 4 * BB;
    int*   n_pos    = (int*)  (ws + off); off += 4 * BB;
    float* hard     = (float*)(ws + off); off += 4 * BB;
    int*   done     = (int*)  (ws + off); off += 4;
    // no memset needed: every buffer is fully written before it is read each iteration
    // (done zeroed by k_prep, which precedes k_topk in-stream)

    k_prep<<<BB, 1024, 0, stream>>>(gt_boxes, (const float4*)priors, pfo, done);

    dim3 gB(NB3, BB);
    k_ce<<<gB, 256, 0, stream>>>(pred_scores, (const float4*)pred_locs, gt_boxes, gt_labels,
                                 (const float4*)priors, pfo, ceneg,
                                 pp_posce, pp_sl1, pp_np);

    k_topk<<<BB, 512, 0, stream>>>(ceneg, pp_posce, pp_sl1, pp_np,
                                   hard, posce_b, sl1_b, n_pos, done, (float*)d_out);
}

// Round 5
// 339.249 us; speedup vs baseline: 7.5042x; 1.1171x over previous
//
#include <hip/hip_runtime.h>
#include <cstdint>
#include <cstddef>

#define BB 64
#define PP 8732
#define OO 32
#define CC 81
#define NR 64     // rows (priors) per k_ce block
#define NB3 137   // ceil(8732/64); 136 full blocks + one 28-row tail
#define NQ 4      // k_prep quadrants per image
#define QP 2183   // priors per quadrant (4*2183 == 8732 exactly)

// ---------- kernel 1: per-object best prior, quadrant-partial ----------
// grid (NQ, BB). thread t -> (object o = t>>5, slice s = t&31) within the quadrant.
// One (iou, prior) register pair per thread (round-3 lesson: arrays spill).
// 4-way ILP per iteration (round-4 lesson: 1-deep chain is latency-bound, 88 us).
__global__ __launch_bounds__(1024) void k_prep(
    const float* __restrict__ gt_boxes,      // [B,O,4] coco pixel
    const float4* __restrict__ priors,       // [P] cxcy
    unsigned long long* __restrict__ part,   // [B,NQ,O] packed (iou_bits<<32)|(~p)
    int* __restrict__ done)
{
    int q = blockIdx.x, b = blockIdx.y, t = threadIdx.x;
    if (q == 0 && b == 0 && t == 0) *done = 0;   // counter for k_topk's fused final
    int o = t >> 5, s = t & 31;
    __shared__ float4 s_pr[1024];            // 16 KB prior chunk
    const float* g = gt_boxes + ((size_t)b * OO + o) * 4;
    float x1 = g[0] / 224.0f, y1 = g[1] / 224.0f;
    float x2 = (g[0] + g[2]) / 224.0f, y2 = (g[1] + g[3]) / 224.0f;
    float area = (x2 - x1) * (y2 - y1);
    float best = -1.0f; int bp = 0;
    int p0 = q * QP;
    for (int base = 0; base < QP; base += 1024) {
        int idx = base + t;
        if (idx < QP) s_pr[t] = priors[p0 + idx];
        __syncthreads();
        int lim = QP - base; if (lim > 1024) lim = 1024;
        for (int j = s; j < lim; j += 128) {      // 4 independent IoUs per iteration
            float iou4[4]; int jj4[4];
            #pragma unroll
            for (int u = 0; u < 4; ++u) {
                int jj = j + 32 * u;
                jj4[u] = jj;
                if (jj < lim) {
                    float4 pr = s_pr[jj];
                    float px1 = pr.x - pr.z * 0.5f, py1 = pr.y - pr.w * 0.5f;
                    float px2 = pr.x + pr.z * 0.5f, py2 = pr.y + pr.w * 0.5f;
                    float parea = (px2 - px1) * (py2 - py1);
                    float lx = fmaxf(x1, px1), ly = fmaxf(y1, py1);
                    float rx = fminf(x2, px2), ry = fminf(y2, py2);
                    float w = fmaxf(rx - lx, 0.0f), h = fmaxf(ry - ly, 0.0f);
                    float inter = w * h;
                    iou4[u] = inter / (area + parea - inter);
                } else iou4[u] = -2.0f;           // can't win
            }
            #pragma unroll
            for (int u = 0; u < 4; ++u)           // ascending order: strict > keeps smallest p
                if (iou4[u] > best) { best = iou4[u]; bp = p0 + base + jj4[u]; }
        }
        __syncthreads();
    }
    // packed (iou, ~p) max across the 32 slices of this object (contiguous half-wave)
    unsigned long long v = ((unsigned long long)__float_as_uint(best) << 32)
                         | (unsigned long long)(0xFFFFFFFFu - (unsigned)bp);
    #pragma unroll
    for (int sh = 16; sh >= 1; sh >>= 1) {
        unsigned long long u = __shfl_xor(v, sh, 32);
        if (u > v) v = u;                    // larger iou, then smaller p
    }
    if (s == 0) part[((size_t)b * NQ + q) * OO + o] = v;
}

// ---------- kernel 2: fused match + CE + loc loss; 64 rows/block, LDS-staged scores ----------
__global__ __launch_bounds__(256) void k_ce(
    const float* __restrict__ scores,        // [B,P,C]
    const float4* __restrict__ pred_locs,
    const float* __restrict__ gt_boxes,
    const int* __restrict__ gt_labels,
    const float4* __restrict__ priors,
    const unsigned long long* __restrict__ part,
    float* __restrict__ ceneg,
    float* __restrict__ pp_posce, float* __restrict__ pp_sl1,
    int* __restrict__ pp_np)
{
    int b = blockIdx.y, tid = threadIdx.x;
    int row0 = blockIdx.x * NR;
    int nrows = PP - row0; if (nrows > NR) nrows = NR;   // 64 or 28 (tail)

    __shared__ float sv[NR * CC];            // 20736 B staged scores
    __shared__ float4 s_pr[NR];
    __shared__ float bx1[OO], by1[OO], bx2[OO], by2[OO], bar[OO];
    __shared__ int s_lab[OO];
    __shared__ int s_pfo[OO];
    __shared__ int s_force[NR];
    __shared__ float s_cn[NR];
    __shared__ float s_posce, s_sl1;
    __shared__ int s_np;

    if (tid == 0) { s_posce = 0.f; s_sl1 = 0.f; s_np = 0; }
    if (tid < OO) {
        const float* g = gt_boxes + ((size_t)b * OO + tid) * 4;
        float x1 = g[0] / 224.0f, y1 = g[1] / 224.0f;
        float x2 = (g[0] + g[2]) / 224.0f, y2 = (g[1] + g[3]) / 224.0f;
        bx1[tid] = x1; by1[tid] = y1; bx2[tid] = x2; by2[tid] = y2;
        bar[tid] = (x2 - x1) * (y2 - y1);
        s_lab[tid] = gt_labels[b * OO + tid];
        // fold the NQ quadrant partials -> global best prior for this object (L2-hot)
        const unsigned long long* pb = part + (size_t)b * NQ * OO + tid;
        unsigned long long m = pb[0];
        #pragma unroll
        for (int qq = 1; qq < NQ; ++qq) {
            unsigned long long v = pb[qq * OO];
            if (v > m) m = v;                // larger iou, then smaller p
        }
        s_pfo[tid] = (int)(0xFFFFFFFFu - (unsigned)(m & 0xFFFFFFFFull));
    }
    if (tid < NR) {
        s_force[tid] = -1;
        if (row0 + tid < PP) s_pr[tid] = priors[row0 + tid];
    }
    __syncthreads();
    if (tid == 0) {                           // ascending o = numpy last-wins on collisions
        #pragma unroll
        for (int o = 0; o < OO; ++o) {
            int rp = s_pfo[o] - row0;
            if (rp >= 0 && rp < nrows) s_force[rp] = o;
        }
    }
    // stage scores: exact float4 count, 16B-aligned for every block (nrows*81 % 4 == 0)
    {
        const float4* src4 = (const float4*)(scores + ((size_t)b * PP + row0) * CC);
        int nvec = nrows * CC / 4;            // 1296 or 567
        float4* dst = (float4*)sv;
        for (int i = tid; i < nvec; i += 256) dst[i] = src4[i];
    }
    __syncthreads();

    int g = tid >> 4, lane = tid & 15;        // 16 groups x 16 lanes; group g: rows g+16j
    #pragma unroll
    for (int j = 0; j < 4; ++j) {
        int r = g + 16 * j;
        if (r < nrows) {                      // uniform across the 16-lane group
            float4 pq = s_pr[r];
            float px1 = pq.x - pq.z * 0.5f, py1 = pq.y - pq.w * 0.5f;
            float px2 = pq.x + pq.z * 0.5f, py2 = pq.y + pq.w * 0.5f;
            float parea = (px2 - px1) * (py2 - py1);
            // per-prior argmax over 32 objects: 2 objects/lane + 4-step butterfly
            float bi; int bo;
            {
                int o1 = lane, o2 = lane + 16;
                float lx = fmaxf(bx1[o1], px1), ly = fmaxf(by1[o1], py1);
                float rx = fminf(bx2[o1], px2), ry = fminf(by2[o1], py2);
                float w1 = fmaxf(rx - lx, 0.0f), h1 = fmaxf(ry - ly, 0.0f);
                float in1 = w1 * h1;
                float i1 = in1 / (bar[o1] + parea - in1);
                lx = fmaxf(bx1[o2], px1); ly = fmaxf(by1[o2], py1);
                rx = fminf(bx2[o2], px2); ry = fminf(by2[o2], py2);
                float w2 = fmaxf(rx - lx, 0.0f), h2 = fmaxf(ry - ly, 0.0f);
                float in2 = w2 * h2;
                float i2 = in2 / (bar[o2] + parea - in2);
                bi = i1; bo = o1;
                if (i2 > bi) { bi = i2; bo = o2; }    // strict > : smaller o on ties
                unsigned long long pk = ((unsigned long long)__float_as_uint(bi) << 32)
                                      | (unsigned long long)(0xFFFFFFFFu - (unsigned)bo);
                #pragma unroll
                for (int s = 8; s >= 1; s >>= 1) {
                    unsigned long long u = __shfl_xor(pk, s, 16);
                    if (u > pk) pk = u;
                }
                bi = __uint_as_float((unsigned)(pk >> 32));
                bo = (int)(0xFFFFFFFFu - (unsigned)(pk & 0xFFFFFFFFull));
            }
            int fo = s_force[r];
            int lab, ob;
            if (fo >= 0) { ob = fo; lab = s_lab[fo]; }           // forced positive (ovl=1.0)
            else         { ob = bo; lab = (bi < 0.5f) ? 0 : s_lab[bo]; }
            // CE from LDS
            float se = 0.f, xl = 0.f;
            #pragma unroll
            for (int k = 0; k < 6; ++k) {
                int c = lane + 16 * k;
                if (c < CC) {
                    float vv = sv[r * CC + c];
                    se += __expf(vv);
                    if (c == lab) xl = vv;
                }
            }
            #pragma unroll
            for (int s = 8; s >= 1; s >>= 1) {
                se += __shfl_xor(se, s, 16);
                xl += __shfl_xor(xl, s, 16);
            }
            if (lane == 0) {
                float ce = fmaxf(__logf(se) - xl, 0.0f);   // >=0 (radix select assumes)
                float cn = ce;
                if (lab != 0) {
                    cn = 0.f;
                    float4 pl = pred_locs[(size_t)b * PP + row0 + r];
                    float x1 = bx1[ob], y1 = by1[ob], x2 = bx2[ob], y2 = by2[ob];
                    float cx = (x1 + x2) * 0.5f, cy = (y1 + y2) * 0.5f;
                    float w = x2 - x1, h = y2 - y1;
                    float tx = (cx - pq.x) / (pq.z / 10.0f);
                    float ty = (cy - pq.y) / (pq.w / 10.0f);
                    float tw = __logf(w / pq.z) * 5.0f;
                    float th = __logf(h / pq.w) * 5.0f;
                    float d0 = fabsf(pl.x - tx), d1 = fabsf(pl.y - ty);
                    float d2 = fabsf(pl.z - tw), d3 = fabsf(pl.w - th);
                    float sl = (d0 < 1.f ? 0.5f * d0 * d0 : d0 - 0.5f)
                             + (d1 < 1.f ? 0.5f * d1 * d1 : d1 - 0.5f)
                             + (d2 < 1.f ? 0.5f * d2 * d2 : d2 - 0.5f)
                             + (d3 < 1.f ? 0.5f * d3 * d3 : d3 - 0.5f);
                    atomicAdd(&s_posce, ce);
                    atomicAdd(&s_sl1, sl);
                    atomicAdd(&s_np, 1);
                }
                s_cn[r] = cn;
            }
        }
    }
    __syncthreads();
    if (tid < nrows) ceneg[(size_t)b * PP + row0 + tid] = s_cn[tid];
    if (tid == 0) {
        int slot = b * NB3 + blockIdx.x;      // dedicated slot: zero global atomics
        pp_posce[slot] = s_posce;
        pp_sl1[slot]   = s_sl1;
        pp_np[slot]    = s_np;
    }
}

// ---------- kernel 3: fold partials + exact top-K via 4-pass radix select + fused final ----------
__global__ __launch_bounds__(512) void k_topk(
    const float* __restrict__ ceneg,
    const float* __restrict__ pp_posce, const float* __restrict__ pp_sl1,
    const int* __restrict__ pp_np,
    float* __restrict__ hard, float* __restrict__ posce_b,
    float* __restrict__ sl1_b, int* __restrict__ n_pos,
    int* __restrict__ done, float* __restrict__ out)
{
    int b = blockIdx.x, tid = threadIdx.x;
    __shared__ float4 sv4[PP / 4];           // 8732/4 = 2183 (34928 B)
    __shared__ int hist[8][256];             // per-wave histograms
    __shared__ int hsum[256];
    __shared__ int s_i[8];
    __shared__ float s_f[8], s_f2[8];
    __shared__ int s_bcast;
    __shared__ unsigned s_sel;
    __shared__ int s_krem;
    __shared__ int s_last;
    // fold per-block partials for this image
    float pc = 0.f, sl = 0.f; int np = 0;
    for (int i = tid; i < NB3; i += 512) {
        pc += pp_posce[b * NB3 + i];
        sl += pp_sl1[b * NB3 + i];
        np += pp_np[b * NB3 + i];
    }
    #pragma unroll
    for (int s = 32; s >= 1; s >>= 1) {
        pc += __shfl_xor(pc, s, 64);
        sl += __shfl_xor(sl, s, 64);
        np += __shfl_xor(np, s, 64);
    }
    int wid = tid >> 6;
    if ((tid & 63) == 0) { s_i[wid] = np; s_f[wid] = pc; s_f2[wid] = sl; }
    // stage ce_neg into LDS (float4)
    const float4* src = (const float4*)(ceneg + (size_t)b * PP);
    for (int i = tid; i < PP / 4; i += 512) sv4[i] = src[i];
    __syncthreads();
    if (tid == 0) {
        int n = 0; float fp = 0.f, fs = 0.f;
        #pragma unroll
        for (int k = 0; k < 8; ++k) { n += s_i[k]; fp += s_f[k]; fs += s_f2[k]; }
        n_pos[b] = n; posce_b[b] = fp; sl1_b[b] = fs;
        s_bcast = n;
        int K0 = 3 * (n > 1 ? n : 1);
        if (K0 > PP) K0 = PP;
        s_sel = 0u; s_krem = K0;
    }
    __syncthreads();
    np = s_bcast;
    int K = 3 * (np > 1 ? np : 1);
    if (K > PP) K = PP;
    // ---- radix select: exact bits of K-th largest (values >= 0 so uint order == float order)
    #pragma unroll
    for (int s = 24; s >= 0; s -= 8) {
        for (int i = tid; i < 8 * 256; i += 512) ((int*)hist)[i] = 0;
        __syncthreads();
        unsigned pref = s_sel; int krem = s_krem;
        int hs = s + 8;
        unsigned prefhi = (hs >= 32) ? 0u : (pref >> (hs & 31));
        for (int i = tid; i < PP / 4; i += 512) {
            float4 q = sv4[i];
            float vals[4] = {q.x, q.y, q.z, q.w};
            #pragma unroll
            for (int c4 = 0; c4 < 4; ++c4) {
                unsigned bts = __float_as_uint(vals[c4]);
                bool ok = (hs >= 32) || ((bts >> (hs & 31)) == prefhi);
                if (ok) atomicAdd(&hist[wid][(bts >> s) & 255], 1);
            }
        }
        __syncthreads();
        if (tid < 256) {
            int t = 0;
            #pragma unroll
            for (int k = 0; k < 8; ++k) t += hist[k][tid];
            hsum[tid] = t;
        }
        __syncthreads();
        if (tid < 64) {
            int ln = tid;
            int cum = 0;
            for (int c = 3; c >= 0; --c) {
                int h = hsum[c * 64 + ln];
                int suff = h;                      // descending suffix-sum within chunk
                #pragma unroll
                for (int off = 1; off < 64; off <<= 1) {
                    int t = __shfl_down(suff, off);
                    if (ln + off < 64) suff += t;
                }
                int ctot = __shfl(suff, 0);        // total of this chunk
                if (cum + ctot >= krem) {          // K-th bin is in this chunk
                    unsigned long long m = __ballot(cum + suff >= krem);
                    int l = 63 - __builtin_clzll(m);
                    int suffl = __shfl(suff, l);
                    int hl = __shfl(h, l);
                    if (ln == 0) {
                        s_sel = pref | ((unsigned)(c * 64 + l) << s);
                        s_krem = krem - (cum + suffl - hl);
                    }
                    break;
                }
                cum += ctot;
            }
        }
        __syncthreads();
    }
    float vk = __uint_as_float(s_sel);   // exact K-th largest value
    // ---- sum of top-K (ties at vk handled exactly)
    float sm = 0.f; int cg = 0;
    for (int i = tid; i < PP / 4; i += 512) {
        float4 q = sv4[i];
        if (q.x > vk) { sm += q.x; cg++; }
        if (q.y > vk) { sm += q.y; cg++; }
        if (q.z > vk) { sm += q.z; cg++; }
        if (q.w > vk) { sm += q.w; cg++; }
    }
    #pragma unroll
    for (int s = 32; s >= 1; s >>= 1) {
        sm += __shfl_xor(sm, s, 64);
        cg += __shfl_xor(cg, s, 64);
    }
    if ((tid & 63) == 0) { s_f[wid] = sm; s_i[wid] = cg; }
    __syncthreads();
    if (tid == 0) {
        float S = 0.f; int CG = 0;
        #pragma unroll
        for (int k = 0; k < 8; ++k) { S += s_f[k]; CG += s_i[k]; }
        hard[b] = S + (float)(K - CG) * vk;
    }
    // ---- fused final: last of the 64 blocks folds per-image results (fence in 64 blocks only)
    __threadfence();
    if (tid == 0) s_last = (atomicAdd(done, 1) == BB - 1) ? 1 : 0;
    __syncthreads();
    if (s_last) {
        __threadfence();
        if (tid < 64) {
            int t = tid;                    // BB == 64 == one wave
            int np2 = n_pos[t];
            float h2 = hard[t], pc2 = posce_b[t], sl2 = sl1_b[t];
            float cl = (float)(np2 > 1 ? np2 : 1);
            int tp = np2; float hs2 = h2; float cls = cl;
            #pragma unroll
            for (int sft = 32; sft >= 1; sft >>= 1) {
                tp  += __shfl_xor(tp, sft, 64);
                hs2 += __shfl_xor(hs2, sft, 64);
                cls += __shfl_xor(cls, sft, 64);
                pc2 += __shfl_xor(pc2, sft, 64);
                sl2 += __shfl_xor(sl2, sft, 64);
            }
            if (t == 0) {
                float conf = (hs2 + pc2) / cls;
                float loc = 0.f;
                if (tp > 0) {
                    int den = tp * 4; if (den < 1) den = 1;
                    loc = sl2 / (float)den;
                }
                out[0] = conf + loc;
            }
        }
    }
}

extern "C" void kernel_launch(void* const* d_in, const int* in_sizes, int n_in,
                              void* d_out, int out_size, void* d_ws, size_t ws_size,
                              hipStream_t stream)
{
    const float* pred_locs   = (const float*)d_in[0];
    const float* pred_scores = (const float*)d_in[1];
    const float* gt_boxes    = (const float*)d_in[2];
    const int*   gt_labels   = (const int*)d_in[3];
    const float* priors      = (const float*)d_in[4];

    char* ws = (char*)d_ws;
    const size_t npf = (size_t)BB * PP;          // 558,848
    size_t off = 0;
    float* ceneg = (float*)(ws + off); off += 4 * npf;   // 16B-aligned
    unsigned long long* part = (unsigned long long*)(ws + off); off += 8 * (size_t)BB * NQ * OO;
    float* pp_posce = (float*)(ws + off); off += 4 * (size_t)BB * NB3;
    float* pp_sl1   = (float*)(ws + off); off += 4 * (size_t)BB * NB3;
    int*   pp_np    = (int*)  (ws + off); off += 4 * (size_t)BB * NB3;
    float* posce_b  = (float*)(ws + off); off += 4 * BB;
    float* sl1_b    = (float*)(ws + off); off += 4 * BB;
    int*   n_pos    = (int*)  (ws + off); off += 4 * BB;
    float* hard     = (float*)(ws + off); off += 4 * BB;
    int*   done     = (int*)  (ws + off); off += 4;
    // no memset needed: every buffer is fully written before it is read each iteration
    // (done zeroed by k_prep, which precedes k_topk in-stream)

    dim3 gP(NQ, BB);
    k_prep<<<gP, 1024, 0, stream>>>(gt_boxes, (const float4*)priors, part, done);

    dim3 gB(NB3, BB);
    k_ce<<<gB, 256, 0, stream>>>(pred_scores, (const float4*)pred_locs, gt_boxes, gt_labels,
                                 (const float4*)priors, part, ceneg,
                                 pp_posce, pp_sl1, pp_np);

    k_topk<<<BB, 512, 0, stream>>>(ceneg, pp_posce, pp_sl1, pp_np,
                                   hard, posce_b, sl1_b, n_pos, done, (float*)d_out);
}

// Round 6
// 333.398 us; speedup vs baseline: 7.6359x; 1.0175x over previous
//
#include <hip/hip_runtime.h>
#include <cstdint>
#include <cstddef>

#define BB 64
#define PP 8732
#define OO 32
#define CC 81
#define NQ 4      // k_prep quadrants per image
#define QP 2183   // priors per quadrant (4*2183 == 8732 exactly)
#define NR4 128   // rows (priors) per k_ce block
#define NB4 69    // ceil(8732/128); 68 full + one 28-row tail

// ---------- kernel 1: per-object best prior, quadrant-partial ----------
// grid (NQ, BB). thread t -> (object o = t>>5, slice s = t&31) within the quadrant.
// One (iou, prior) register pair per thread (round-3 lesson: arrays spill).
// 4-way ILP per iteration (round-4 lesson: 1-deep chain is latency-bound).
__global__ __launch_bounds__(1024) void k_prep(
    const float* __restrict__ gt_boxes,      // [B,O,4] coco pixel
    const float4* __restrict__ priors,       // [P] cxcy
    unsigned long long* __restrict__ part,   // [B,NQ,O] packed (iou_bits<<32)|(~p)
    int* __restrict__ done)
{
    int q = blockIdx.x, b = blockIdx.y, t = threadIdx.x;
    if (q == 0 && b == 0 && t == 0) *done = 0;   // counter for k_topk's fused final
    int o = t >> 5, s = t & 31;
    __shared__ float4 s_pr[1024];            // 16 KB prior chunk
    const float* g = gt_boxes + ((size_t)b * OO + o) * 4;
    float x1 = g[0] / 224.0f, y1 = g[1] / 224.0f;
    float x2 = (g[0] + g[2]) / 224.0f, y2 = (g[1] + g[3]) / 224.0f;
    float area = (x2 - x1) * (y2 - y1);
    float best = -1.0f; int bp = 0;
    int p0 = q * QP;
    for (int base = 0; base < QP; base += 1024) {
        int idx = base + t;
        if (idx < QP) s_pr[t] = priors[p0 + idx];
        __syncthreads();
        int lim = QP - base; if (lim > 1024) lim = 1024;
        for (int j = s; j < lim; j += 128) {      // 4 independent IoUs per iteration
            float iou4[4]; int jj4[4];
            #pragma unroll
            for (int u = 0; u < 4; ++u) {
                int jj = j + 32 * u;
                jj4[u] = jj;
                if (jj < lim) {
                    float4 pr = s_pr[jj];
                    float px1 = pr.x - pr.z * 0.5f, py1 = pr.y - pr.w * 0.5f;
                    float px2 = pr.x + pr.z * 0.5f, py2 = pr.y + pr.w * 0.5f;
                    float parea = (px2 - px1) * (py2 - py1);
                    float lx = fmaxf(x1, px1), ly = fmaxf(y1, py1);
                    float rx = fminf(x2, px2), ry = fminf(y2, py2);
                    float w = fmaxf(rx - lx, 0.0f), h = fmaxf(ry - ly, 0.0f);
                    float inter = w * h;
                    iou4[u] = inter / (area + parea - inter);
                } else iou4[u] = -2.0f;           // can't win
            }
            #pragma unroll
            for (int u = 0; u < 4; ++u)           // ascending order: strict > keeps smallest p
                if (iou4[u] > best) { best = iou4[u]; bp = p0 + base + jj4[u]; }
        }
        __syncthreads();
    }
    // packed (iou, ~p) max across the 32 slices of this object
    unsigned long long v = ((unsigned long long)__float_as_uint(best) << 32)
                         | (unsigned long long)(0xFFFFFFFFu - (unsigned)bp);
    #pragma unroll
    for (int sh = 16; sh >= 1; sh >>= 1) {
        unsigned long long u = __shfl_xor(v, sh, 32);
        if (u > v) v = u;                    // larger iou, then smaller p
    }
    if (s == 0) part[((size_t)b * NQ + q) * OO + o] = v;
}

// ---------- kernel 2: fused match + CE + loc loss; ONE PRIOR PER LANE ----------
// 128 threads / 128 rows / 41.5 KB staged scores. Zero cross-lane ops in the
// main path (round-5 lesson: u64-shfl butterflies = ds_bpermute storms, 105 us
// at 12% HBM). LDS read addr = 81*l + c -> bank (17l+c)%32, 17 odd => only the
// free 2-way alias.
__global__ __launch_bounds__(128) void k_ce(
    const float* __restrict__ scores,        // [B,P,C]
    const float4* __restrict__ pred_locs,
    const float* __restrict__ gt_boxes,
    const int* __restrict__ gt_labels,
    const float4* __restrict__ priors,
    const unsigned long long* __restrict__ part,
    float* __restrict__ ceneg,
    float* __restrict__ pp_posce, float* __restrict__ pp_sl1,
    int* __restrict__ pp_np)
{
    int b = blockIdx.y, tid = threadIdx.x;
    int row0 = blockIdx.x * NR4;
    int nrows = PP - row0; if (nrows > NR4) nrows = NR4;   // 128 or 28 (tail)

    __shared__ float sv[NR4 * CC];           // 41472 B staged scores
    __shared__ float bx1[OO], by1[OO], bx2[OO], by2[OO], bar[OO];
    __shared__ int s_lab[OO];
    __shared__ int s_pfo[OO];
    __shared__ int s_force[NR4];
    __shared__ float s_posce, s_sl1;
    __shared__ int s_np;

    if (tid == 0) { s_posce = 0.f; s_sl1 = 0.f; s_np = 0; }
    if (tid < OO) {
        const float* g = gt_boxes + ((size_t)b * OO + tid) * 4;
        float x1 = g[0] / 224.0f, y1 = g[1] / 224.0f;
        float x2 = (g[0] + g[2]) / 224.0f, y2 = (g[1] + g[3]) / 224.0f;
        bx1[tid] = x1; by1[tid] = y1; bx2[tid] = x2; by2[tid] = y2;
        bar[tid] = (x2 - x1) * (y2 - y1);
        s_lab[tid] = gt_labels[b * OO + tid];
        // fold NQ quadrant partials -> global best prior per object (L2-hot)
        const unsigned long long* pb = part + (size_t)b * NQ * OO + tid;
        unsigned long long m = pb[0];
        #pragma unroll
        for (int qq = 1; qq < NQ; ++qq) {
            unsigned long long v = pb[qq * OO];
            if (v > m) m = v;                // larger iou, then smaller p
        }
        s_pfo[tid] = (int)(0xFFFFFFFFu - (unsigned)(m & 0xFFFFFFFFull));
    }
    s_force[tid] = -1;                        // blockDim == NR4
    __syncthreads();
    if (tid == 0) {                           // ascending o = numpy last-wins on collisions
        #pragma unroll
        for (int o = 0; o < OO; ++o) {
            int rp = s_pfo[o] - row0;
            if (rp >= 0 && rp < nrows) s_force[rp] = o;
        }
    }
    // stage scores: coalesced float4, 4-deep pipelined (16B-aligned for every block:
    // row0*81*4 % 16 == 0 since row0 % 4 == 0; nvec exact: nrows*81 % 4 == 0)
    {
        const float4* src4 = (const float4*)(scores + ((size_t)b * PP + row0) * CC);
        float4* dst = (float4*)sv;
        int nvec = nrows * CC / 4;            // 2592 or 567
        for (int base = 0; base < nvec; base += 512) {
            int i0 = base + tid, i1 = i0 + 128, i2 = i0 + 256, i3 = i0 + 384;
            bool v0 = i0 < nvec, v1 = i1 < nvec, v2 = i2 < nvec, v3 = i3 < nvec;
            float4 t0, t1, t2, t3;
            if (v0) t0 = src4[i0];
            if (v1) t1 = src4[i1];
            if (v2) t2 = src4[i2];
            if (v3) t3 = src4[i3];
            if (v0) dst[i0] = t0;
            if (v1) dst[i1] = t1;
            if (v2) dst[i2] = t2;
            if (v3) dst[i3] = t3;
        }
    }
    __syncthreads();

    if (tid < nrows) {
        int p = row0 + tid;
        float4 pq = priors[p];                // coalesced
        float px1 = pq.x - pq.z * 0.5f, py1 = pq.y - pq.w * 0.5f;
        float px2 = pq.x + pq.z * 0.5f, py2 = pq.y + pq.w * 0.5f;
        float parea = (px2 - px1) * (py2 - py1);
        // per-prior argmax over 32 objects, serial in registers (LDS broadcasts)
        float bi = -1.0f; int bo = 0;
        #pragma unroll
        for (int o = 0; o < OO; ++o) {
            float lx = fmaxf(bx1[o], px1), ly = fmaxf(by1[o], py1);
            float rx = fminf(bx2[o], px2), ry = fminf(by2[o], py2);
            float w = fmaxf(rx - lx, 0.0f), h = fmaxf(ry - ly, 0.0f);
            float inter = w * h;
            float iou = inter / (bar[o] + parea - inter);
            if (iou > bi) { bi = iou; bo = o; }   // strict > : first max (numpy argmax)
        }
        int fo = s_force[tid];
        int lab, ob;
        if (fo >= 0) { ob = fo; lab = s_lab[fo]; }           // forced positive (ovl=1.0)
        else         { ob = bo; lab = (bi < 0.5f) ? 0 : s_lab[bo]; }
        // CE from own LDS row, 4 accumulators for ILP
        const float* row = sv + tid * CC;
        float se0 = 0.f, se1 = 0.f, se2 = 0.f, se3 = 0.f;
        #pragma unroll
        for (int c = 0; c < 80; c += 4) {
            se0 += __expf(row[c]);
            se1 += __expf(row[c + 1]);
            se2 += __expf(row[c + 2]);
            se3 += __expf(row[c + 3]);
        }
        float se = (se0 + se1) + (se2 + se3) + __expf(row[80]);
        float xl = row[lab];
        float ce = fmaxf(__logf(se) - xl, 0.0f);   // >=0 (radix select assumes)
        float cn = ce;
        if (lab != 0) {
            cn = 0.f;
            float4 pl = pred_locs[(size_t)b * PP + p];
            float x1 = bx1[ob], y1 = by1[ob], x2 = bx2[ob], y2 = by2[ob];
            float cx = (x1 + x2) * 0.5f, cy = (y1 + y2) * 0.5f;
            float w = x2 - x1, h = y2 - y1;
            float tx = (cx - pq.x) / (pq.z / 10.0f);
            float ty = (cy - pq.y) / (pq.w / 10.0f);
            float tw = __logf(w / pq.z) * 5.0f;
            float th = __logf(h / pq.w) * 5.0f;
            float d0 = fabsf(pl.x - tx), d1 = fabsf(pl.y - ty);
            float d2 = fabsf(pl.z - tw), d3 = fabsf(pl.w - th);
            float sl = (d0 < 1.f ? 0.5f * d0 * d0 : d0 - 0.5f)
                     + (d1 < 1.f ? 0.5f * d1 * d1 : d1 - 0.5f)
                     + (d2 < 1.f ? 0.5f * d2 * d2 : d2 - 0.5f)
                     + (d3 < 1.f ? 0.5f * d3 * d3 : d3 - 0.5f);
            atomicAdd(&s_posce, ce);   // LDS atomics, rare (positives only)
            atomicAdd(&s_sl1, sl);
            atomicAdd(&s_np, 1);
        }
        ceneg[(size_t)b * PP + p] = cn;       // coalesced
    }
    __syncthreads();
    if (tid == 0) {
        int slot = b * NB4 + blockIdx.x;      // dedicated slot: zero global atomics
        pp_posce[slot] = s_posce;
        pp_sl1[slot]   = s_sl1;
        pp_np[slot]    = s_np;
    }
}

// ---------- kernel 3: fold partials + exact top-K via 4-pass radix select + fused final ----------
__global__ __launch_bounds__(512) void k_topk(
    const float* __restrict__ ceneg,
    const float* __restrict__ pp_posce, const float* __restrict__ pp_sl1,
    const int* __restrict__ pp_np,
    float* __restrict__ hard, float* __restrict__ posce_b,
    float* __restrict__ sl1_b, int* __restrict__ n_pos,
    int* __restrict__ done, float* __restrict__ out)
{
    int b = blockIdx.x, tid = threadIdx.x;
    __shared__ float4 sv4[PP / 4];           // 8732/4 = 2183 (34928 B)
    __shared__ int hist[8][256];             // per-wave histograms
    __shared__ int hsum[256];
    __shared__ int s_i[8];
    __shared__ float s_f[8], s_f2[8];
    __shared__ int s_bcast;
    __shared__ unsigned s_sel;
    __shared__ int s_krem;
    __shared__ int s_last;
    // fold per-block partials for this image
    float pc = 0.f, sl = 0.f; int np = 0;
    for (int i = tid; i < NB4; i += 512) {
        pc += pp_posce[b * NB4 + i];
        sl += pp_sl1[b * NB4 + i];
        np += pp_np[b * NB4 + i];
    }
    #pragma unroll
    for (int s = 32; s >= 1; s >>= 1) {
        pc += __shfl_xor(pc, s, 64);
        sl += __shfl_xor(sl, s, 64);
        np += __shfl_xor(np, s, 64);
    }
    int wid = tid >> 6;
    if ((tid & 63) == 0) { s_i[wid] = np; s_f[wid] = pc; s_f2[wid] = sl; }
    // stage ce_neg into LDS (float4)
    const float4* src = (const float4*)(ceneg + (size_t)b * PP);
    for (int i = tid; i < PP / 4; i += 512) sv4[i] = src[i];
    __syncthreads();
    if (tid == 0) {
        int n = 0; float fp = 0.f, fs = 0.f;
        #pragma unroll
        for (int k = 0; k < 8; ++k) { n += s_i[k]; fp += s_f[k]; fs += s_f2[k]; }
        n_pos[b] = n; posce_b[b] = fp; sl1_b[b] = fs;
        s_bcast = n;
        int K0 = 3 * (n > 1 ? n : 1);
        if (K0 > PP) K0 = PP;
        s_sel = 0u; s_krem = K0;
    }
    __syncthreads();
    np = s_bcast;
    int K = 3 * (np > 1 ? np : 1);
    if (K > PP) K = PP;
    // ---- radix select: exact bits of K-th largest (values >= 0 so uint order == float order)
    #pragma unroll
    for (int s = 24; s >= 0; s -= 8) {
        for (int i = tid; i < 8 * 256; i += 512) ((int*)hist)[i] = 0;
        __syncthreads();
        unsigned pref = s_sel; int krem = s_krem;
        int hs = s + 8;
        unsigned prefhi = (hs >= 32) ? 0u : (pref >> (hs & 31));
        for (int i = tid; i < PP / 4; i += 512) {
            float4 q = sv4[i];
            float vals[4] = {q.x, q.y, q.z, q.w};
            #pragma unroll
            for (int c4 = 0; c4 < 4; ++c4) {
                unsigned bts = __float_as_uint(vals[c4]);
                bool ok = (hs >= 32) || ((bts >> (hs & 31)) == prefhi);
                if (ok) atomicAdd(&hist[wid][(bts >> s) & 255], 1);
            }
        }
        __syncthreads();
        if (tid < 256) {
            int t = 0;
            #pragma unroll
            for (int k = 0; k < 8; ++k) t += hist[k][tid];
            hsum[tid] = t;
        }
        __syncthreads();
        if (tid < 64) {
            int ln = tid;
            int cum = 0;
            for (int c = 3; c >= 0; --c) {
                int h = hsum[c * 64 + ln];
                int suff = h;                      // descending suffix-sum within chunk
                #pragma unroll
                for (int off = 1; off < 64; off <<= 1) {
                    int t = __shfl_down(suff, off);
                    if (ln + off < 64) suff += t;
                }
                int ctot = __shfl(suff, 0);        // total of this chunk
                if (cum + ctot >= krem) {          // K-th bin is in this chunk
                    unsigned long long m = __ballot(cum + suff >= krem);
                    int l = 63 - __builtin_clzll(m);
                    int suffl = __shfl(suff, l);
                    int hl = __shfl(h, l);
                    if (ln == 0) {
                        s_sel = pref | ((unsigned)(c * 64 + l) << s);
                        s_krem = krem - (cum + suffl - hl);
                    }
                    break;
                }
                cum += ctot;
            }
        }
        __syncthreads();
    }
    float vk = __uint_as_float(s_sel);   // exact K-th largest value
    // ---- sum of top-K (ties at vk handled exactly)
    float sm = 0.f; int cg = 0;
    for (int i = tid; i < PP / 4; i += 512) {
        float4 q = sv4[i];
        if (q.x > vk) { sm += q.x; cg++; }
        if (q.y > vk) { sm += q.y; cg++; }
        if (q.z > vk) { sm += q.z; cg++; }
        if (q.w > vk) { sm += q.w; cg++; }
    }
    #pragma unroll
    for (int s = 32; s >= 1; s >>= 1) {
        sm += __shfl_xor(sm, s, 64);
        cg += __shfl_xor(cg, s, 64);
    }
    if ((tid & 63) == 0) { s_f[wid] = sm; s_i[wid] = cg; }
    __syncthreads();
    if (tid == 0) {
        float S = 0.f; int CG = 0;
        #pragma unroll
        for (int k = 0; k < 8; ++k) { S += s_f[k]; CG += s_i[k]; }
        hard[b] = S + (float)(K - CG) * vk;
    }
    // ---- fused final: last of the 64 blocks folds per-image results (fence in 64 blocks only)
    __threadfence();
    if (tid == 0) s_last = (atomicAdd(done, 1) == BB - 1) ? 1 : 0;
    __syncthreads();
    if (s_last) {
        __threadfence();
        if (tid < 64) {
            int t = tid;                    // BB == 64 == one wave
            int np2 = n_pos[t];
            float h2 = hard[t], pc2 = posce_b[t], sl2 = sl1_b[t];
            float cl = (float)(np2 > 1 ? np2 : 1);
            int tp = np2; float hs2 = h2; float cls = cl;
            #pragma unroll
            for (int sft = 32; sft >= 1; sft >>= 1) {
                tp  += __shfl_xor(tp, sft, 64);
                hs2 += __shfl_xor(hs2, sft, 64);
                cls += __shfl_xor(cls, sft, 64);
                pc2 += __shfl_xor(pc2, sft, 64);
                sl2 += __shfl_xor(sl2, sft, 64);
            }
            if (t == 0) {
                float conf = (hs2 + pc2) / cls;
                float loc = 0.f;
                if (tp > 0) {
                    int den = tp * 4; if (den < 1) den = 1;
                    loc = sl2 / (float)den;
                }
                out[0] = conf + loc;
            }
        }
    }
}

extern "C" void kernel_launch(void* const* d_in, const int* in_sizes, int n_in,
                              void* d_out, int out_size, void* d_ws, size_t ws_size,
                              hipStream_t stream)
{
    const float* pred_locs   = (const float*)d_in[0];
    const float* pred_scores = (const float*)d_in[1];
    const float* gt_boxes    = (const float*)d_in[2];
    const int*   gt_labels   = (const int*)d_in[3];
    const float* priors      = (const float*)d_in[4];

    char* ws = (char*)d_ws;
    const size_t npf = (size_t)BB * PP;          // 558,848
    size_t off = 0;
    float* ceneg = (float*)(ws + off); off += 4 * npf;   // 16B-aligned
    unsigned long long* part = (unsigned long long*)(ws + off); off += 8 * (size_t)BB * NQ * OO;
    float* pp_posce = (float*)(ws + off); off += 4 * (size_t)BB * NB4;
    float* pp_sl1   = (float*)(ws + off); off += 4 * (size_t)BB * NB4;
    int*   pp_np    = (int*)  (ws + off); off += 4 * (size_t)BB * NB4;
    float* posce_b  = (float*)(ws + off); off += 4 * BB;
    float* sl1_b    = (float*)(ws + off); off += 4 * BB;
    int*   n_pos    = (int*)  (ws + off); off += 4 * BB;
    float* hard     = (float*)(ws + off); off += 4 * BB;
    int*   done     = (int*)  (ws + off); off += 4;
    // no memset needed: every buffer is fully written before it is read each iteration
    // (done zeroed by k_prep, which precedes k_topk in-stream)

    dim3 gP(NQ, BB);
    k_prep<<<gP, 1024, 0, stream>>>(gt_boxes, (const float4*)priors, part, done);

    dim3 gB(NB4, BB);
    k_ce<<<gB, 128, 0, stream>>>(pred_scores, (const float4*)pred_locs, gt_boxes, gt_labels,
                                 (const float4*)priors, part, ceneg,
                                 pp_posce, pp_sl1, pp_np);

    k_topk<<<BB, 512, 0, stream>>>(ceneg, pp_posce, pp_sl1, pp_np,
                                   hard, posce_b, sl1_b, n_pos, done, (float*)d_out);
}

// Round 7
// 325.315 us; speedup vs baseline: 7.8256x; 1.0248x over previous
//
#include <hip/hip_runtime.h>
#include <cstdint>
#include <cstddef>

#define BB 64
#define PP 8732
#define OO 32
#define CC 81
#define NQ 4      // k_prep quadrants per image
#define QP 2183   // priors per quadrant (4*2183 == 8732 exactly)
#define NR5 256   // rows (priors) per k_ce block
#define NB5 35    // ceil(8732/256); 34 full + one 28-row tail

// ---------- kernel 1: per-object best prior, quadrant-partial ----------
// grid (NQ, BB). thread t -> (object o = t>>5, slice s = t&31) within the quadrant.
// One (iou, prior) register pair per thread (round-3 lesson: arrays spill).
// 4-way ILP per iteration (round-4 lesson: 1-deep chain is latency-bound).
__global__ __launch_bounds__(1024) void k_prep(
    const float* __restrict__ gt_boxes,      // [B,O,4] coco pixel
    const float4* __restrict__ priors,       // [P] cxcy
    unsigned long long* __restrict__ part,   // [B,NQ,O] packed (iou_bits<<32)|(~p)
    int* __restrict__ done)
{
    int q = blockIdx.x, b = blockIdx.y, t = threadIdx.x;
    if (q == 0 && b == 0 && t == 0) *done = 0;   // counter for k_topk's fused final
    int o = t >> 5, s = t & 31;
    __shared__ float4 s_pr[1024];            // 16 KB prior chunk
    const float* g = gt_boxes + ((size_t)b * OO + o) * 4;
    float x1 = g[0] / 224.0f, y1 = g[1] / 224.0f;
    float x2 = (g[0] + g[2]) / 224.0f, y2 = (g[1] + g[3]) / 224.0f;
    float area = (x2 - x1) * (y2 - y1);
    float best = -1.0f; int bp = 0;
    int p0 = q * QP;
    for (int base = 0; base < QP; base += 1024) {
        int idx = base + t;
        if (idx < QP) s_pr[t] = priors[p0 + idx];
        __syncthreads();
        int lim = QP - base; if (lim > 1024) lim = 1024;
        for (int j = s; j < lim; j += 128) {      // 4 independent IoUs per iteration
            float iou4[4]; int jj4[4];
            #pragma unroll
            for (int u = 0; u < 4; ++u) {
                int jj = j + 32 * u;
                jj4[u] = jj;
                if (jj < lim) {
                    float4 pr = s_pr[jj];
                    float px1 = pr.x - pr.z * 0.5f, py1 = pr.y - pr.w * 0.5f;
                    float px2 = pr.x + pr.z * 0.5f, py2 = pr.y + pr.w * 0.5f;
                    float parea = (px2 - px1) * (py2 - py1);
                    float lx = fmaxf(x1, px1), ly = fmaxf(y1, py1);
                    float rx = fminf(x2, px2), ry = fminf(y2, py2);
                    float w = fmaxf(rx - lx, 0.0f), h = fmaxf(ry - ly, 0.0f);
                    float inter = w * h;
                    iou4[u] = inter / (area + parea - inter);
                } else iou4[u] = -2.0f;           // can't win
            }
            #pragma unroll
            for (int u = 0; u < 4; ++u)           // ascending order: strict > keeps smallest p
                if (iou4[u] > best) { best = iou4[u]; bp = p0 + base + jj4[u]; }
        }
        __syncthreads();
    }
    // packed (iou, ~p) max across the 32 slices of this object
    unsigned long long v = ((unsigned long long)__float_as_uint(best) << 32)
                         | (unsigned long long)(0xFFFFFFFFu - (unsigned)bp);
    #pragma unroll
    for (int sh = 16; sh >= 1; sh >>= 1) {
        unsigned long long u = __shfl_xor(v, sh, 32);
        if (u > v) v = u;                    // larger iou, then smaller p
    }
    if (s == 0) part[((size_t)b * NQ + q) * OO + o] = v;
}

// ---------- kernel 2: fused match + loc + CE, two-phase, NO score staging ----------
// Lessons driving this structure:
//  R5: 16-lane u64 butterflies + LDS staging -> issue-bound, 105 us (VALU 51%, HBM 12%)
//  R6: per-lane rows + 41.5 KB LDS stage -> 3 blocks/CU, 6 waves, latency-exposed, ~100 us
// Fix: tiny LDS (~3.5 KB) => ~32 waves/CU; phase A per-lane match (zero cross-lane),
// phase B 16-lane-group CE with direct coalesced global reads (8 shfl/prior only).
__global__ __launch_bounds__(256) void k_ce(
    const float* __restrict__ scores,        // [B,P,C]
    const float4* __restrict__ pred_locs,
    const float* __restrict__ gt_boxes,
    const int* __restrict__ gt_labels,
    const float4* __restrict__ priors,
    const unsigned long long* __restrict__ part,
    float* __restrict__ ceneg,
    float* __restrict__ pp_posce, float* __restrict__ pp_sl1,
    int* __restrict__ pp_np)
{
    int b = blockIdx.y, tid = threadIdx.x;
    int row0 = blockIdx.x * NR5;
    int nrows = PP - row0; if (nrows > NR5) nrows = NR5;   // 256 or 28 (tail)

    __shared__ float bx1[OO], by1[OO], bx2[OO], by2[OO], bar[OO];
    __shared__ int s_lab[OO];
    __shared__ int s_pfo[OO];
    __shared__ int s_ol[NR5];                // per-row label (phase A -> B)
    __shared__ float s_cn[NR5];
    __shared__ float s_posce, s_sl1;
    __shared__ int s_np;

    if (tid == 0) { s_posce = 0.f; s_sl1 = 0.f; s_np = 0; }
    if (tid < OO) {
        const float* g = gt_boxes + ((size_t)b * OO + tid) * 4;
        float x1 = g[0] / 224.0f, y1 = g[1] / 224.0f;
        float x2 = (g[0] + g[2]) / 224.0f, y2 = (g[1] + g[3]) / 224.0f;
        bx1[tid] = x1; by1[tid] = y1; bx2[tid] = x2; by2[tid] = y2;
        bar[tid] = (x2 - x1) * (y2 - y1);
        s_lab[tid] = gt_labels[b * OO + tid];
        // fold NQ quadrant partials -> global best prior per object (L2-hot)
        const unsigned long long* pb = part + (size_t)b * NQ * OO + tid;
        unsigned long long m = pb[0];
        #pragma unroll
        for (int qq = 1; qq < NQ; ++qq) {
            unsigned long long v = pb[qq * OO];
            if (v > m) m = v;                // larger iou, then smaller p
        }
        s_pfo[tid] = (int)(0xFFFFFFFFu - (unsigned)(m & 0xFFFFFFFFull));
    }
    __syncthreads();

    // ---- phase A: one prior per lane -- match + forced detect + loc loss ----
    if (tid < nrows) {
        int p = row0 + tid;
        float4 pq = priors[p];                // coalesced
        float px1 = pq.x - pq.z * 0.5f, py1 = pq.y - pq.w * 0.5f;
        float px2 = pq.x + pq.z * 0.5f, py2 = pq.y + pq.w * 0.5f;
        float parea = (px2 - px1) * (py2 - py1);
        float bi = -1.0f; int bo = 0; int fo = -1;
        #pragma unroll 8
        for (int o = 0; o < OO; ++o) {
            float lx = fmaxf(bx1[o], px1), ly = fmaxf(by1[o], py1);
            float rx = fminf(bx2[o], px2), ry = fminf(by2[o], py2);
            float w = fmaxf(rx - lx, 0.0f), h = fmaxf(ry - ly, 0.0f);
            float inter = w * h;
            float iou = inter / (bar[o] + parea - inter);
            if (iou > bi) { bi = iou; bo = o; }   // strict > : first max (numpy argmax)
            if (s_pfo[o] == p) fo = o;            // ascending o = numpy last-wins
        }
        int lab, ob;
        if (fo >= 0) { ob = fo; lab = s_lab[fo]; }           // forced positive (ovl=1.0)
        else         { ob = bo; lab = (bi < 0.5f) ? 0 : s_lab[bo]; }
        s_ol[tid] = lab;
        if (lab != 0) {                        // rare (~1% of priors): loc loss here
            float4 pl = pred_locs[(size_t)b * PP + p];
            float x1 = bx1[ob], y1 = by1[ob], x2 = bx2[ob], y2 = by2[ob];
            float cx = (x1 + x2) * 0.5f, cy = (y1 + y2) * 0.5f;
            float w = x2 - x1, h = y2 - y1;
            float tx = (cx - pq.x) / (pq.z / 10.0f);
            float ty = (cy - pq.y) / (pq.w / 10.0f);
            float tw = __logf(w / pq.z) * 5.0f;
            float th = __logf(h / pq.w) * 5.0f;
            float d0 = fabsf(pl.x - tx), d1 = fabsf(pl.y - ty);
            float d2 = fabsf(pl.z - tw), d3 = fabsf(pl.w - th);
            float sl = (d0 < 1.f ? 0.5f * d0 * d0 : d0 - 0.5f)
                     + (d1 < 1.f ? 0.5f * d1 * d1 : d1 - 0.5f)
                     + (d2 < 1.f ? 0.5f * d2 * d2 : d2 - 0.5f)
                     + (d3 < 1.f ? 0.5f * d3 * d3 : d3 - 0.5f);
            atomicAdd(&s_sl1, sl);
            atomicAdd(&s_np, 1);
        }
    }
    __syncthreads();

    // ---- phase B: 16 lanes per prior -- CE from direct coalesced global reads ----
    {
        int g = tid >> 4, lane = tid & 15;    // 16 groups; wave = 4 consecutive rows
        #pragma unroll 4
        for (int j = 0; j < 16; ++j) {
            int r = g + 16 * j;
            if (r < nrows) {
                int lab = s_ol[r];
                const float* row = scores + ((size_t)b * PP + row0 + r) * CC;
                float se = 0.f, xl = 0.f;
                #pragma unroll
                for (int k = 0; k < 6; ++k) {
                    int c = lane + 16 * k;
                    if (c < CC) {
                        float v = row[c];
                        se += __expf(v);
                        if (c == lab) xl = v;
                    }
                }
                #pragma unroll
                for (int s = 8; s >= 1; s >>= 1) {
                    se += __shfl_xor(se, s, 16);
                    xl += __shfl_xor(xl, s, 16);
                }
                if (lane == 0) {
                    float ce = fmaxf(__logf(se) - xl, 0.0f);   // >=0 (radix select assumes)
                    if (lab != 0) { atomicAdd(&s_posce, ce); s_cn[r] = 0.f; }
                    else s_cn[r] = ce;
                }
            }
        }
    }
    __syncthreads();
    if (tid < nrows) ceneg[(size_t)b * PP + row0 + tid] = s_cn[tid];   // coalesced
    if (tid == 0) {
        int slot = b * NB5 + blockIdx.x;      // dedicated slot: zero global atomics
        pp_posce[slot] = s_posce;
        pp_sl1[slot]   = s_sl1;
        pp_np[slot]    = s_np;
    }
}

// ---------- kernel 3: fold partials + exact top-K via 4-pass radix select + fused final ----------
__global__ __launch_bounds__(512) void k_topk(
    const float* __restrict__ ceneg,
    const float* __restrict__ pp_posce, const float* __restrict__ pp_sl1,
    const int* __restrict__ pp_np,
    float* __restrict__ hard, float* __restrict__ posce_b,
    float* __restrict__ sl1_b, int* __restrict__ n_pos,
    int* __restrict__ done, float* __restrict__ out)
{
    int b = blockIdx.x, tid = threadIdx.x;
    __shared__ float4 sv4[PP / 4];           // 8732/4 = 2183 (34928 B)
    __shared__ int hist[8][256];             // per-wave histograms
    __shared__ int hsum[256];
    __shared__ int s_i[8];
    __shared__ float s_f[8], s_f2[8];
    __shared__ int s_bcast;
    __shared__ unsigned s_sel;
    __shared__ int s_krem;
    __shared__ int s_last;
    // fold per-block partials for this image
    float pc = 0.f, sl = 0.f; int np = 0;
    for (int i = tid; i < NB5; i += 512) {
        pc += pp_posce[b * NB5 + i];
        sl += pp_sl1[b * NB5 + i];
        np += pp_np[b * NB5 + i];
    }
    #pragma unroll
    for (int s = 32; s >= 1; s >>= 1) {
        pc += __shfl_xor(pc, s, 64);
        sl += __shfl_xor(sl, s, 64);
        np += __shfl_xor(np, s, 64);
    }
    int wid = tid >> 6;
    if ((tid & 63) == 0) { s_i[wid] = np; s_f[wid] = pc; s_f2[wid] = sl; }
    // stage ce_neg into LDS (float4)
    const float4* src = (const float4*)(ceneg + (size_t)b * PP);
    for (int i = tid; i < PP / 4; i += 512) sv4[i] = src[i];
    __syncthreads();
    if (tid == 0) {
        int n = 0; float fp = 0.f, fs = 0.f;
        #pragma unroll
        for (int k = 0; k < 8; ++k) { n += s_i[k]; fp += s_f[k]; fs += s_f2[k]; }
        n_pos[b] = n; posce_b[b] = fp; sl1_b[b] = fs;
        s_bcast = n;
        int K0 = 3 * (n > 1 ? n : 1);
        if (K0 > PP) K0 = PP;
        s_sel = 0u; s_krem = K0;
    }
    __syncthreads();
    np = s_bcast;
    int K = 3 * (np > 1 ? np : 1);
    if (K > PP) K = PP;
    // ---- radix select: exact bits of K-th largest (values >= 0 so uint order == float order)
    #pragma unroll
    for (int s = 24; s >= 0; s -= 8) {
        for (int i = tid; i < 8 * 256; i += 512) ((int*)hist)[i] = 0;
        __syncthreads();
        unsigned pref = s_sel; int krem = s_krem;
        int hs = s + 8;
        unsigned prefhi = (hs >= 32) ? 0u : (pref >> (hs & 31));
        for (int i = tid; i < PP / 4; i += 512) {
            float4 q = sv4[i];
            float vals[4] = {q.x, q.y, q.z, q.w};
            #pragma unroll
            for (int c4 = 0; c4 < 4; ++c4) {
                unsigned bts = __float_as_uint(vals[c4]);
                bool ok = (hs >= 32) || ((bts >> (hs & 31)) == prefhi);
                if (ok) atomicAdd(&hist[wid][(bts >> s) & 255], 1);
            }
        }
        __syncthreads();
        if (tid < 256) {
            int t = 0;
            #pragma unroll
            for (int k = 0; k < 8; ++k) t += hist[k][tid];
            hsum[tid] = t;
        }
        __syncthreads();
        if (tid < 64) {
            int ln = tid;
            int cum = 0;
            for (int c = 3; c >= 0; --c) {
                int h = hsum[c * 64 + ln];
                int suff = h;                      // descending suffix-sum within chunk
                #pragma unroll
                for (int off = 1; off < 64; off <<= 1) {
                    int t = __shfl_down(suff, off);
                    if (ln + off < 64) suff += t;
                }
                int ctot = __shfl(suff, 0);        // total of this chunk
                if (cum + ctot >= krem) {          // K-th bin is in this chunk
                    unsigned long long m = __ballot(cum + suff >= krem);
                    int l = 63 - __builtin_clzll(m);
                    int suffl = __shfl(suff, l);
                    int hl = __shfl(h, l);
                    if (ln == 0) {
                        s_sel = pref | ((unsigned)(c * 64 + l) << s);
                        s_krem = krem - (cum + suffl - hl);
                    }
                    break;
                }
                cum += ctot;
            }
        }
        __syncthreads();
    }
    float vk = __uint_as_float(s_sel);   // exact K-th largest value
    // ---- sum of top-K (ties at vk handled exactly)
    float sm = 0.f; int cg = 0;
    for (int i = tid; i < PP / 4; i += 512) {
        float4 q = sv4[i];
        if (q.x > vk) { sm += q.x; cg++; }
        if (q.y > vk) { sm += q.y; cg++; }
        if (q.z > vk) { sm += q.z; cg++; }
        if (q.w > vk) { sm += q.w; cg++; }
    }
    #pragma unroll
    for (int s = 32; s >= 1; s >>= 1) {
        sm += __shfl_xor(sm, s, 64);
        cg += __shfl_xor(cg, s, 64);
    }
    if ((tid & 63) == 0) { s_f[wid] = sm; s_i[wid] = cg; }
    __syncthreads();
    if (tid == 0) {
        float S = 0.f; int CG = 0;
        #pragma unroll
        for (int k = 0; k < 8; ++k) { S += s_f[k]; CG += s_i[k]; }
        hard[b] = S + (float)(K - CG) * vk;
    }
    // ---- fused final: last of the 64 blocks folds per-image results (fence in 64 blocks only)
    __threadfence();
    if (tid == 0) s_last = (atomicAdd(done, 1) == BB - 1) ? 1 : 0;
    __syncthreads();
    if (s_last) {
        __threadfence();
        if (tid < 64) {
            int t = tid;                    // BB == 64 == one wave
            int np2 = n_pos[t];
            float h2 = hard[t], pc2 = posce_b[t], sl2 = sl1_b[t];
            float cl = (float)(np2 > 1 ? np2 : 1);
            int tp = np2; float hs2 = h2; float cls = cl;
            #pragma unroll
            for (int sft = 32; sft >= 1; sft >>= 1) {
                tp  += __shfl_xor(tp, sft, 64);
                hs2 += __shfl_xor(hs2, sft, 64);
                cls += __shfl_xor(cls, sft, 64);
                pc2 += __shfl_xor(pc2, sft, 64);
                sl2 += __shfl_xor(sl2, sft, 64);
            }
            if (t == 0) {
                float conf = (hs2 + pc2) / cls;
                float loc = 0.f;
                if (tp > 0) {
                    int den = tp * 4; if (den < 1) den = 1;
                    loc = sl2 / (float)den;
                }
                out[0] = conf + loc;
            }
        }
    }
}

extern "C" void kernel_launch(void* const* d_in, const int* in_sizes, int n_in,
                              void* d_out, int out_size, void* d_ws, size_t ws_size,
                              hipStream_t stream)
{
    const float* pred_locs   = (const float*)d_in[0];
    const float* pred_scores = (const float*)d_in[1];
    const float* gt_boxes    = (const float*)d_in[2];
    const int*   gt_labels   = (const int*)d_in[3];
    const float* priors      = (const float*)d_in[4];

    char* ws = (char*)d_ws;
    const size_t npf = (size_t)BB * PP;          // 558,848
    size_t off = 0;
    float* ceneg = (float*)(ws + off); off += 4 * npf;   // 16B-aligned
    unsigned long long* part = (unsigned long long*)(ws + off); off += 8 * (size_t)BB * NQ * OO;
    float* pp_posce = (float*)(ws + off); off += 4 * (size_t)BB * NB5;
    float* pp_sl1   = (float*)(ws + off); off += 4 * (size_t)BB * NB5;
    int*   pp_np    = (int*)  (ws + off); off += 4 * (size_t)BB * NB5;
    float* posce_b  = (float*)(ws + off); off += 4 * BB;
    float* sl1_b    = (float*)(ws + off); off += 4 * BB;
    int*   n_pos    = (int*)  (ws + off); off += 4 * BB;
    float* hard     = (float*)(ws + off); off += 4 * BB;
    int*   done     = (int*)  (ws + off); off += 4;
    // no memset needed: every buffer is fully written before it is read each iteration
    // (done zeroed by k_prep, which precedes k_topk in-stream)

    dim3 gP(NQ, BB);
    k_prep<<<gP, 1024, 0, stream>>>(gt_boxes, (const float4*)priors, part, done);

    dim3 gB(NB5, BB);
    k_ce<<<gB, 256, 0, stream>>>(pred_scores, (const float4*)pred_locs, gt_boxes, gt_labels,
                                 (const float4*)priors, part, ceneg,
                                 pp_posce, pp_sl1, pp_np);

    k_topk<<<BB, 512, 0, stream>>>(ceneg, pp_posce, pp_sl1, pp_np,
                                   hard, posce_b, sl1_b, n_pos, done, (float*)d_out);
}

// Round 8
// 320.036 us; speedup vs baseline: 7.9547x; 1.0165x over previous
//
#include <hip/hip_runtime.h>
#include <cstdint>
#include <cstddef>

#define BB 64
#define PP 8732
#define OO 32
#define CC 81
#define NQ 4      // k_prep quadrants per image
#define QP 2183   // priors per quadrant (4*2183 == 8732 exactly)
#define NR5 256   // rows (priors) per k_ce block
#define NB5 35    // ceil(8732/256); 34 full + one 28-row tail

// ---------- kernel 1: per-object best prior, quadrant-partial ----------
// grid (NQ, BB). thread t -> (object o = t>>5, slice s = t&31) within the quadrant.
// One (iou, prior) register pair per thread (round-3 lesson: arrays spill).
// 4-way ILP per iteration (round-4 lesson: 1-deep chain is latency-bound).
__global__ __launch_bounds__(1024) void k_prep(
    const float* __restrict__ gt_boxes,      // [B,O,4] coco pixel
    const float4* __restrict__ priors,       // [P] cxcy
    unsigned long long* __restrict__ part,   // [B,NQ,O] packed (iou_bits<<32)|(~p)
    int* __restrict__ done)
{
    int q = blockIdx.x, b = blockIdx.y, t = threadIdx.x;
    if (q == 0 && b == 0 && t == 0) *done = 0;   // counter for k_topk's fused final
    int o = t >> 5, s = t & 31;
    __shared__ float4 s_pr[1024];            // 16 KB prior chunk
    const float* g = gt_boxes + ((size_t)b * OO + o) * 4;
    float x1 = g[0] / 224.0f, y1 = g[1] / 224.0f;
    float x2 = (g[0] + g[2]) / 224.0f, y2 = (g[1] + g[3]) / 224.0f;
    float area = (x2 - x1) * (y2 - y1);
    float best = -1.0f; int bp = 0;
    int p0 = q * QP;
    for (int base = 0; base < QP; base += 1024) {
        int idx = base + t;
        if (idx < QP) s_pr[t] = priors[p0 + idx];
        __syncthreads();
        int lim = QP - base; if (lim > 1024) lim = 1024;
        for (int j = s; j < lim; j += 128) {      // 4 independent IoUs per iteration
            float iou4[4]; int jj4[4];
            #pragma unroll
            for (int u = 0; u < 4; ++u) {
                int jj = j + 32 * u;
                jj4[u] = jj;
                if (jj < lim) {
                    float4 pr = s_pr[jj];
                    float px1 = pr.x - pr.z * 0.5f, py1 = pr.y - pr.w * 0.5f;
                    float px2 = pr.x + pr.z * 0.5f, py2 = pr.y + pr.w * 0.5f;
                    float parea = (px2 - px1) * (py2 - py1);
                    float lx = fmaxf(x1, px1), ly = fmaxf(y1, py1);
                    float rx = fminf(x2, px2), ry = fminf(y2, py2);
                    float w = fmaxf(rx - lx, 0.0f), h = fmaxf(ry - ly, 0.0f);
                    float inter = w * h;
                    iou4[u] = inter / (area + parea - inter);
                } else iou4[u] = -2.0f;           // can't win
            }
            #pragma unroll
            for (int u = 0; u < 4; ++u)           // ascending order: strict > keeps smallest p
                if (iou4[u] > best) { best = iou4[u]; bp = p0 + base + jj4[u]; }
        }
        __syncthreads();
    }
    // packed (iou, ~p) max across the 32 slices of this object
    unsigned long long v = ((unsigned long long)__float_as_uint(best) << 32)
                         | (unsigned long long)(0xFFFFFFFFu - (unsigned)bp);
    #pragma unroll
    for (int sh = 16; sh >= 1; sh >>= 1) {
        unsigned long long u = __shfl_xor(v, sh, 32);
        if (u > v) v = u;                    // larger iou, then smaller p
    }
    if (s == 0) part[((size_t)b * NQ + q) * OO + o] = v;
}

// ---------- kernel 2: fused match + loc + CE, two-phase ----------
// Lessons: R5 u64-butterflies = 105 us issue-bound; R6 41.5KB LDS = occupancy-starved;
// R7 16-lane CE (15/81 idle cols, 6 strided loads, 8 wide shuffles) = 92 us, VALU-bound.
// This version: phase B uses 8 LANES PER ROW -- 81 = 10*8+1 so all lanes productive,
// 10 immediate-offset dword loads (32B/octet contiguous), 2 exp accumulators,
// 6 narrow shuffles/row. Tiny LDS (~3.6 KB) keeps occupancy wave-limited.
__global__ __launch_bounds__(256) void k_ce(
    const float* __restrict__ scores,        // [B,P,C]
    const float4* __restrict__ pred_locs,
    const float* __restrict__ gt_boxes,
    const int* __restrict__ gt_labels,
    const float4* __restrict__ priors,
    const unsigned long long* __restrict__ part,
    float* __restrict__ ceneg,
    float* __restrict__ pp_posce, float* __restrict__ pp_sl1,
    int* __restrict__ pp_np)
{
    int b = blockIdx.y, tid = threadIdx.x;
    int row0 = blockIdx.x * NR5;
    int nrows = PP - row0; if (nrows > NR5) nrows = NR5;   // 256 or 28 (tail)

    __shared__ float bx1[OO], by1[OO], bx2[OO], by2[OO], bar[OO];
    __shared__ int s_lab[OO];
    __shared__ int s_pfo[OO];
    __shared__ int s_ol[NR5];                // per-row label (phase A -> B)
    __shared__ float s_cn[NR5];
    __shared__ float s_posce, s_sl1;
    __shared__ int s_np;

    if (tid == 0) { s_posce = 0.f; s_sl1 = 0.f; s_np = 0; }
    if (tid < OO) {
        const float* g = gt_boxes + ((size_t)b * OO + tid) * 4;
        float x1 = g[0] / 224.0f, y1 = g[1] / 224.0f;
        float x2 = (g[0] + g[2]) / 224.0f, y2 = (g[1] + g[3]) / 224.0f;
        bx1[tid] = x1; by1[tid] = y1; bx2[tid] = x2; by2[tid] = y2;
        bar[tid] = (x2 - x1) * (y2 - y1);
        s_lab[tid] = gt_labels[b * OO + tid];
        // fold NQ quadrant partials -> global best prior per object (L2-hot)
        const unsigned long long* pb = part + (size_t)b * NQ * OO + tid;
        unsigned long long m = pb[0];
        #pragma unroll
        for (int qq = 1; qq < NQ; ++qq) {
            unsigned long long v = pb[qq * OO];
            if (v > m) m = v;                // larger iou, then smaller p
        }
        s_pfo[tid] = (int)(0xFFFFFFFFu - (unsigned)(m & 0xFFFFFFFFull));
    }
    __syncthreads();

    // ---- phase A: one prior per lane -- match + forced detect + loc loss ----
    if (tid < nrows) {
        int p = row0 + tid;
        float4 pq = priors[p];                // coalesced
        float px1 = pq.x - pq.z * 0.5f, py1 = pq.y - pq.w * 0.5f;
        float px2 = pq.x + pq.z * 0.5f, py2 = pq.y + pq.w * 0.5f;
        float parea = (px2 - px1) * (py2 - py1);
        float bi = -1.0f; int bo = 0; int fo = -1;
        #pragma unroll 8
        for (int o = 0; o < OO; ++o) {
            float lx = fmaxf(bx1[o], px1), ly = fmaxf(by1[o], py1);
            float rx = fminf(bx2[o], px2), ry = fminf(by2[o], py2);
            float w = fmaxf(rx - lx, 0.0f), h = fmaxf(ry - ly, 0.0f);
            float inter = w * h;
            float iou = inter / (bar[o] + parea - inter);
            if (iou > bi) { bi = iou; bo = o; }   // strict > : first max (numpy argmax)
            if (s_pfo[o] == p) fo = o;            // ascending o = numpy last-wins
        }
        int lab, ob;
        if (fo >= 0) { ob = fo; lab = s_lab[fo]; }           // forced positive (ovl=1.0)
        else         { ob = bo; lab = (bi < 0.5f) ? 0 : s_lab[bo]; }
        s_ol[tid] = lab;
        if (lab != 0) {                        // rare (~1% of priors): loc loss here
            float4 pl = pred_locs[(size_t)b * PP + p];
            float x1 = bx1[ob], y1 = by1[ob], x2 = bx2[ob], y2 = by2[ob];
            float cx = (x1 + x2) * 0.5f, cy = (y1 + y2) * 0.5f;
            float w = x2 - x1, h = y2 - y1;
            float tx = (cx - pq.x) / (pq.z / 10.0f);
            float ty = (cy - pq.y) / (pq.w / 10.0f);
            float tw = __logf(w / pq.z) * 5.0f;
            float th = __logf(h / pq.w) * 5.0f;
            float d0 = fabsf(pl.x - tx), d1 = fabsf(pl.y - ty);
            float d2 = fabsf(pl.z - tw), d3 = fabsf(pl.w - th);
            float sl = (d0 < 1.f ? 0.5f * d0 * d0 : d0 - 0.5f)
                     + (d1 < 1.f ? 0.5f * d1 * d1 : d1 - 0.5f)
                     + (d2 < 1.f ? 0.5f * d2 * d2 : d2 - 0.5f)
                     + (d3 < 1.f ? 0.5f * d3 * d3 : d3 - 0.5f);
            atomicAdd(&s_sl1, sl);
            atomicAdd(&s_np, 1);
        }
    }
    __syncthreads();

    // ---- phase B: 8 lanes per prior -- CE, immediate-offset loads, octet reduce ----
    {
        int rloc = tid >> 3;                  // 0..31 (8 consecutive rows per wave)
        int sub = tid & 7;
        #pragma unroll
        for (int j = 0; j < 8; ++j) {
            int r = rloc + 32 * j;
            if (r < nrows) {
                int lab = s_ol[r];
                const float* row = scores + ((size_t)b * PP + row0 + r) * CC + sub;
                float se0 = 0.f, se1 = 0.f, xl = 0.f;
                #pragma unroll
                for (int k = 0; k < 10; k += 2) {  // c = k*8+sub <= 79 always valid
                    float v0 = row[k * 8];
                    float v1 = row[k * 8 + 8];
                    se0 += __expf(v0);
                    se1 += __expf(v1);
                    if (k * 8 + sub == lab) xl = v0;
                    if (k * 8 + 8 + sub == lab) xl = v1;
                }
                float se = se0 + se1;
                if (sub == 0) {                    // tail element c = 80
                    float v80 = row[80];
                    se += __expf(v80);
                    if (lab == 80) xl = v80;
                }
                #pragma unroll
                for (int s = 4; s >= 1; s >>= 1) { // octet reduce (owner's xl propagates)
                    se += __shfl_xor(se, s, 8);
                    xl += __shfl_xor(xl, s, 8);
                }
                if (sub == 0) {
                    float ce = fmaxf(__logf(se) - xl, 0.0f);   // >=0 (radix select assumes)
                    if (lab != 0) { atomicAdd(&s_posce, ce); s_cn[r] = 0.f; }
                    else s_cn[r] = ce;
                }
            }
        }
    }
    __syncthreads();
    if (tid < nrows) ceneg[(size_t)b * PP + row0 + tid] = s_cn[tid];   // coalesced
    if (tid == 0) {
        int slot = b * NB5 + blockIdx.x;      // dedicated slot: zero global atomics
        pp_posce[slot] = s_posce;
        pp_sl1[slot]   = s_sl1;
        pp_np[slot]    = s_np;
    }
}

// ---------- kernel 3: fold partials + exact top-K via 4-pass radix select + fused final ----------
__global__ __launch_bounds__(512) void k_topk(
    const float* __restrict__ ceneg,
    const float* __restrict__ pp_posce, const float* __restrict__ pp_sl1,
    const int* __restrict__ pp_np,
    float* __restrict__ hard, float* __restrict__ posce_b,
    float* __restrict__ sl1_b, int* __restrict__ n_pos,
    int* __restrict__ done, float* __restrict__ out)
{
    int b = blockIdx.x, tid = threadIdx.x;
    __shared__ float4 sv4[PP / 4];           // 8732/4 = 2183 (34928 B)
    __shared__ int hist[8][256];             // per-wave histograms
    __shared__ int hsum[256];
    __shared__ int s_i[8];
    __shared__ float s_f[8], s_f2[8];
    __shared__ int s_bcast;
    __shared__ unsigned s_sel;
    __shared__ int s_krem;
    __shared__ int s_last;
    // fold per-block partials for this image
    float pc = 0.f, sl = 0.f; int np = 0;
    for (int i = tid; i < NB5; i += 512) {
        pc += pp_posce[b * NB5 + i];
        sl += pp_sl1[b * NB5 + i];
        np += pp_np[b * NB5 + i];
    }
    #pragma unroll
    for (int s = 32; s >= 1; s >>= 1) {
        pc += __shfl_xor(pc, s, 64);
        sl += __shfl_xor(sl, s, 64);
        np += __shfl_xor(np, s, 64);
    }
    int wid = tid >> 6;
    if ((tid & 63) == 0) { s_i[wid] = np; s_f[wid] = pc; s_f2[wid] = sl; }
    // stage ce_neg into LDS (float4)
    const float4* src = (const float4*)(ceneg + (size_t)b * PP);
    for (int i = tid; i < PP / 4; i += 512) sv4[i] = src[i];
    __syncthreads();
    if (tid == 0) {
        int n = 0; float fp = 0.f, fs = 0.f;
        #pragma unroll
        for (int k = 0; k < 8; ++k) { n += s_i[k]; fp += s_f[k]; fs += s_f2[k]; }
        n_pos[b] = n; posce_b[b] = fp; sl1_b[b] = fs;
        s_bcast = n;
        int K0 = 3 * (n > 1 ? n : 1);
        if (K0 > PP) K0 = PP;
        s_sel = 0u; s_krem = K0;
    }
    __syncthreads();
    np = s_bcast;
    int K = 3 * (np > 1 ? np : 1);
    if (K > PP) K = PP;
    // ---- radix select: exact bits of K-th largest (values >= 0 so uint order == float order)
    #pragma unroll
    for (int s = 24; s >= 0; s -= 8) {
        for (int i = tid; i < 8 * 256; i += 512) ((int*)hist)[i] = 0;
        __syncthreads();
        unsigned pref = s_sel; int krem = s_krem;
        int hs = s + 8;
        unsigned prefhi = (hs >= 32) ? 0u : (pref >> (hs & 31));
        for (int i = tid; i < PP / 4; i += 512) {
            float4 q = sv4[i];
            float vals[4] = {q.x, q.y, q.z, q.w};
            #pragma unroll
            for (int c4 = 0; c4 < 4; ++c4) {
                unsigned bts = __float_as_uint(vals[c4]);
                bool ok = (hs >= 32) || ((bts >> (hs & 31)) == prefhi);
                if (ok) atomicAdd(&hist[wid][(bts >> s) & 255], 1);
            }
        }
        __syncthreads();
        if (tid < 256) {
            int t = 0;
            #pragma unroll
            for (int k = 0; k < 8; ++k) t += hist[k][tid];
            hsum[tid] = t;
        }
        __syncthreads();
        if (tid < 64) {
            int ln = tid;
            int cum = 0;
            for (int c = 3; c >= 0; --c) {
                int h = hsum[c * 64 + ln];
                int suff = h;                      // descending suffix-sum within chunk
                #pragma unroll
                for (int off = 1; off < 64; off <<= 1) {
                    int t = __shfl_down(suff, off);
                    if (ln + off < 64) suff += t;
                }
                int ctot = __shfl(suff, 0);        // total of this chunk
                if (cum + ctot >= krem) {          // K-th bin is in this chunk
                    unsigned long long m = __ballot(cum + suff >= krem);
                    int l = 63 - __builtin_clzll(m);
                    int suffl = __shfl(suff, l);
                    int hl = __shfl(h, l);
                    if (ln == 0) {
                        s_sel = pref | ((unsigned)(c * 64 + l) << s);
                        s_krem = krem - (cum + suffl - hl);
                    }
                    break;
                }
                cum += ctot;
            }
        }
        __syncthreads();
    }
    float vk = __uint_as_float(s_sel);   // exact K-th largest value
    // ---- sum of top-K (ties at vk handled exactly)
    float sm = 0.f; int cg = 0;
    for (int i = tid; i < PP / 4; i += 512) {
        float4 q = sv4[i];
        if (q.x > vk) { sm += q.x; cg++; }
        if (q.y > vk) { sm += q.y; cg++; }
        if (q.z > vk) { sm += q.z; cg++; }
        if (q.w > vk) { sm += q.w; cg++; }
    }
    #pragma unroll
    for (int s = 32; s >= 1; s >>= 1) {
        sm += __shfl_xor(sm, s, 64);
        cg += __shfl_xor(cg, s, 64);
    }
    if ((tid & 63) == 0) { s_f[wid] = sm; s_i[wid] = cg; }
    __syncthreads();
    if (tid == 0) {
        float S = 0.f; int CG = 0;
        #pragma unroll
        for (int k = 0; k < 8; ++k) { S += s_f[k]; CG += s_i[k]; }
        hard[b] = S + (float)(K - CG) * vk;
    }
    // ---- fused final: last of the 64 blocks folds per-image results (fence in 64 blocks only)
    __threadfence();
    if (tid == 0) s_last = (atomicAdd(done, 1) == BB - 1) ? 1 : 0;
    __syncthreads();
    if (s_last) {
        __threadfence();
        if (tid < 64) {
            int t = tid;                    // BB == 64 == one wave
            int np2 = n_pos[t];
            float h2 = hard[t], pc2 = posce_b[t], sl2 = sl1_b[t];
            float cl = (float)(np2 > 1 ? np2 : 1);
            int tp = np2; float hs2 = h2; float cls = cl;
            #pragma unroll
            for (int sft = 32; sft >= 1; sft >>= 1) {
                tp  += __shfl_xor(tp, sft, 64);
                hs2 += __shfl_xor(hs2, sft, 64);
                cls += __shfl_xor(cls, sft, 64);
                pc2 += __shfl_xor(pc2, sft, 64);
                sl2 += __shfl_xor(sl2, sft, 64);
            }
            if (t == 0) {
                float conf = (hs2 + pc2) / cls;
                float loc = 0.f;
                if (tp > 0) {
                    int den = tp * 4; if (den < 1) den = 1;
                    loc = sl2 / (float)den;
                }
                out[0] = conf + loc;
            }
        }
    }
}

extern "C" void kernel_launch(void* const* d_in, const int* in_sizes, int n_in,
                              void* d_out, int out_size, void* d_ws, size_t ws_size,
                              hipStream_t stream)
{
    const float* pred_locs   = (const float*)d_in[0];
    const float* pred_scores = (const float*)d_in[1];
    const float* gt_boxes    = (const float*)d_in[2];
    const int*   gt_labels   = (const int*)d_in[3];
    const float* priors      = (const float*)d_in[4];

    char* ws = (char*)d_ws;
    const size_t npf = (size_t)BB * PP;          // 558,848
    size_t off = 0;
    float* ceneg = (float*)(ws + off); off += 4 * npf;   // 16B-aligned
    unsigned long long* part = (unsigned long long*)(ws + off); off += 8 * (size_t)BB * NQ * OO;
    float* pp_posce = (float*)(ws + off); off += 4 * (size_t)BB * NB5;
    float* pp_sl1   = (float*)(ws + off); off += 4 * (size_t)BB * NB5;
    int*   pp_np    = (int*)  (ws + off); off += 4 * (size_t)BB * NB5;
    float* posce_b  = (float*)(ws + off); off += 4 * BB;
    float* sl1_b    = (float*)(ws + off); off += 4 * BB;
    int*   n_pos    = (int*)  (ws + off); off += 4 * BB;
    float* hard     = (float*)(ws + off); off += 4 * BB;
    int*   done     = (int*)  (ws + off); off += 4;
    // no memset needed: every buffer is fully written before it is read each iteration
    // (done zeroed by k_prep, which precedes k_topk in-stream)

    dim3 gP(NQ, BB);
    k_prep<<<gP, 1024, 0, stream>>>(gt_boxes, (const float4*)priors, part, done);

    dim3 gB(NB5, BB);
    k_ce<<<gB, 256, 0, stream>>>(pred_scores, (const float4*)pred_locs, gt_boxes, gt_labels,
                                 (const float4*)priors, part, ceneg,
                                 pp_posce, pp_sl1, pp_np);

    k_topk<<<BB, 512, 0, stream>>>(ceneg, pp_posce, pp_sl1, pp_np,
                                   hard, posce_b, sl1_b, n_pos, done, (float*)d_out);
}